// Round 9
// baseline (1214.072 us; speedup 1.0000x reference)
//
#include <hip/hip_runtime.h>
#include <hip/hip_fp16.h>
#include <float.h>

typedef _Float16 f16x8 __attribute__((ext_vector_type(8)));
typedef float f32x4 __attribute__((ext_vector_type(4)));

#define N_PTS 65536
#define D_DIM 512
#define K_EMB 4096

// ---------- screen geometry ----------
#define FBM 128            // rows per screen block
#define FBN 256            // cols per chunk
#define NCH 16             // K_EMB / FBN
#define NDS 16             // D_DIM / 32
#define NT  256            // NCH * NDS steps
#define NBLK 512           // N_PTS / FBM
#define TILE_HB 16384      // 16KB per 256-row hi-tile
#define SLOTS 12288u       // candidate slots per 128-row block

#define GLOAD16(gsrc, ldst)                                                    \
  __builtin_amdgcn_global_load_lds(                                            \
      (const __attribute__((address_space(1))) void*)(gsrc),                   \
      (__attribute__((address_space(3))) void*)(ldst), 16, 0, 0)

#define BAR() asm volatile("s_barrier" ::: "memory")
#define VMCNT(n) asm volatile("s_waitcnt vmcnt(" #n ")" ::: "memory")
#define PRIO(n) __builtin_amdgcn_s_setprio(n)

// ---------------- Kernel 1: fused norms + fp16-hi tile precompute -----------
// bid 0..255: X super-tile (256 rows); bid 256..271: E super-tile.
// Tile layout (16KB per 256-row x 32-half tile): element (row=rg*16+l15,
// k=kq*8+h) at byte ((rg*4+kq)*16 + l15)*16 + h*2.
__global__ void vq_prep(const float* __restrict__ X, const float* __restrict__ E,
                        char* __restrict__ Xpre, char* __restrict__ Epre,
                        float* __restrict__ en, unsigned* __restrict__ enmax,
                        unsigned* __restrict__ xnmax) {
  __shared__ float smax[4];
  const int bid = blockIdx.x;
  const int r = threadIdx.x;
  const int lane = r & 63;
  const int wid = r >> 6;
  const bool isX = bid < 256;
  const float* src = isX ? X + ((size_t)bid * 256 + r) * D_DIM
                         : E + ((size_t)(bid - 256) * 256 + r) * D_DIM;
  char* dstb = isX ? Xpre + (size_t)bid * 16 * TILE_HB
                   : Epre + (size_t)(bid - 256) * 16 * TILE_HB;
  const int rg = r >> 4, l15 = r & 15;
  float nrm = 0.f;
#pragma unroll 4
  for (int ds = 0; ds < 16; ++ds) {
    const float* base = src + ds * 32;
    char* dst = dstb + (size_t)ds * TILE_HB;
#pragma unroll
    for (int kq = 0; kq < 4; ++kq) {
      const float4 a = *(const float4*)(base + kq * 8);
      const float4 b = *(const float4*)(base + kq * 8 + 4);
      nrm += a.x * a.x + a.y * a.y + a.z * a.z + a.w * a.w +
             b.x * b.x + b.y * b.y + b.z * b.z + b.w * b.w;
      f16x8 H;
      H[0] = (_Float16)a.x; H[1] = (_Float16)a.y; H[2] = (_Float16)a.z; H[3] = (_Float16)a.w;
      H[4] = (_Float16)b.x; H[5] = (_Float16)b.y; H[6] = (_Float16)b.z; H[7] = (_Float16)b.w;
      *(f16x8*)(dst + ((size_t)((rg * 4 + kq) * 16 + l15)) * 16) = H;
    }
  }
  if (!isX) en[(bid - 256) * 256 + r] = nrm;
  float mx = nrm;
#pragma unroll
  for (int m = 32; m >= 1; m >>= 1) mx = fmaxf(mx, __shfl_xor(mx, m));
  if (lane == 0) smax[wid] = mx;
  __syncthreads();
  if (r == 0) {
    const float mm = fmaxf(fmaxf(smax[0], smax[1]), fmaxf(smax[2], smax[3]));
    atomicMax(isX ? xnmax : enmax, __float_as_uint(mm));
  }
}

// ---------------- Kernel 2: hh screen GEMM + per-block candidate emission ---
// 512 blocks x 256 thr (4 waves: wm=row-half of 128, wn=col-half of 256).
// LDS ~49KB -> up to 3 blocks/CU co-resident: overlap hides barrier drain.
__global__ __launch_bounds__(256) void vq_screen(
    const char* __restrict__ Xpre, const char* __restrict__ Epre,
    const float* __restrict__ en, const unsigned* __restrict__ enmax,
    const unsigned* __restrict__ xnmax, unsigned* __restrict__ counts,
    unsigned long long* __restrict__ cand, float* __restrict__ hhmin) {
  __shared__ __align__(16) char bufX[2][8192];
  __shared__ __align__(16) char bufE[2][16384];
  __shared__ float argv_[2][FBM];
  __shared__ unsigned s_cnt;

  const int tid = threadIdx.x;
  const int lane = tid & 63;
  const int wid = tid >> 6;
  const int wm = wid >> 1;   // 0..1: 64-row group
  const int wn = wid & 1;    // 0..1: 128-col group
  const int l15 = lane & 15;
  const int lq = lane >> 4;
  const int mt = blockIdx.x;

  unsigned long long* myc = cand + (size_t)mt * SLOTS;
  if (tid == 0) s_cnt = 0;

  const float eps = 0.004f * sqrtf(__uint_as_float(*xnmax) * __uint_as_float(*enmax)) + 0.2f;

#define STAGE_X(g1)                                                            \
  {                                                                            \
    const char* s_ = Xpre + ((size_t)((mt >> 1) * 16 + ((g1) & 15))) * TILE_HB \
                     + (mt & 1) * 8192 + wid * 2048 + lane * 16;               \
    char* d_ = &bufX[(g1) & 1][wid * 2048];                                    \
    GLOAD16(s_, d_); GLOAD16(s_ + 1024, d_ + 1024);                            \
  }
#define STAGE_E(g1)                                                            \
  {                                                                            \
    const char* s_ = Epre + ((size_t)(g1)) * TILE_HB + wid * 4096 + lane * 16; \
    char* d_ = &bufE[(g1) & 1][wid * 4096];                                    \
    GLOAD16(s_, d_); GLOAD16(s_ + 1024, d_ + 1024);                            \
    GLOAD16(s_ + 2048, d_ + 2048); GLOAD16(s_ + 3072, d_ + 3072);              \
  }

  // prologue: step-0 tiles; full drain + barrier (also publishes s_cnt=0)
  STAGE_X(0);
  STAGE_E(0);
  VMCNT(0);
  BAR();

  f32x4 acc[4][8];
  float minv[16];
#pragma unroll
  for (int k = 0; k < 16; ++k) minv[k] = FLT_MAX;

  f16x8 AH[4], BH[8];

  for (int g = 0; g < NT; ++g) {
    const char* XB = &bufX[g & 1][0];
    const char* EB = &bufE[g & 1][0];

    if ((g & 15) == 0) {
#pragma unroll
      for (int i = 0; i < 4; ++i)
#pragma unroll
        for (int j = 0; j < 8; ++j) acc[i][j] = (f32x4)(0.f);
    }

    // ---- P1: prefetch X(g+1); counted drain; read AH + BH[0..3]; 16 MFMA ---
    if (g + 1 < NT) { STAGE_X(g + 1); VMCNT(2); } else { VMCNT(0); }
    BAR();
#pragma unroll
    for (int i = 0; i < 4; ++i)
      AH[i] = *(const f16x8*)(XB + (wm * 4 + i) * 1024 + lane * 16);
#pragma unroll
    for (int j = 0; j < 4; ++j)
      BH[j] = *(const f16x8*)(EB + (wn * 8 + j) * 1024 + lane * 16);
    PRIO(1);
#pragma unroll
    for (int i = 0; i < 4; ++i)
#pragma unroll
      for (int j = 0; j < 4; ++j)
        acc[i][j] = __builtin_amdgcn_mfma_f32_16x16x32_f16(AH[i], BH[j], acc[i][j], 0, 0, 0);
    PRIO(0);

    // ---- P2: prefetch E(g+1); read BH[4..7]; 16 MFMA ----------------------
    if (g + 1 < NT) STAGE_E(g + 1);
    BAR();
#pragma unroll
    for (int j = 4; j < 8; ++j)
      BH[j] = *(const f16x8*)(EB + (wn * 8 + j) * 1024 + lane * 16);
    PRIO(1);
#pragma unroll
    for (int i = 0; i < 4; ++i)
#pragma unroll
      for (int j = 4; j < 8; ++j)
        acc[i][j] = __builtin_amdgcn_mfma_f32_16x16x32_f16(AH[i], BH[j], acc[i][j], 0, 0, 0);
    PRIO(0);

    // ---- chunk end: row-min update + candidate emission (LDS counter) -----
    if ((g & 15) == 15) {
      const int c = g >> 4;
      float ej[8];
#pragma unroll
      for (int j = 0; j < 8; ++j)
        ej[j] = en[c * 256 + wn * 128 + j * 16 + l15];   // L2-hot 16KB table
#pragma unroll
      for (int k = 0; k < 16; ++k) {
        const int i = k >> 2, r = k & 3;
        float dd[8];
        float cm = FLT_MAX;
#pragma unroll
        for (int j = 0; j < 8; ++j) {
          dd[j] = fmaf(-2.f, acc[i][j][r], ej[j]);
          cm = fminf(cm, dd[j]);
        }
#pragma unroll
        for (int m = 1; m <= 8; m <<= 1) cm = fminf(cm, __shfl_xor(cm, m));
        minv[k] = fminf(minv[k], cm);
        const float thr = minv[k] + eps;
        const unsigned grow = (unsigned)(mt * FBM + wm * 64 + i * 16 + lq * 4 + r);
#pragma unroll
        for (int j = 0; j < 8; ++j) {
          if (dd[j] <= thr) {
            const unsigned slot = atomicAdd(&s_cnt, 1u);
            if (slot < SLOTS) {
              const unsigned col = (unsigned)(c * 256 + wn * 128 + j * 16 + l15);
              myc[slot] = ((unsigned long long)((grow << 12) | col) << 32) |
                          __float_as_uint(dd[j]);
            }
          }
        }
      }
    }
  }
#undef STAGE_X
#undef STAGE_E

  // ---- epilogue: per-row final hh-min + count -----------------------------
#pragma unroll
  for (int k = 0; k < 16; ++k) {
    if (l15 == 0)
      argv_[wn][wm * 64 + (k >> 2) * 16 + lq * 4 + (k & 3)] = minv[k];
  }
  __syncthreads();
  if (tid < FBM)
    hhmin[mt * FBM + tid] = fminf(argv_[0][tid], argv_[1][tid]);
  if (tid == 0)
    counts[mt] = (s_cnt < SLOTS) ? s_cnt : SLOTS;
}

// ---------------- Kernel 3: fused resolve (filter + exact dots + gather) ----
// Block b owns rows b*128..b*128+127 exclusively (candidates are block-local).
__global__ __launch_bounds__(256) void vq_resolve(
    const float* __restrict__ X, const float* __restrict__ E,
    const float* __restrict__ en, const unsigned* __restrict__ enmax,
    const unsigned* __restrict__ xnmax, const unsigned* __restrict__ counts,
    const unsigned long long* __restrict__ cand, const float* __restrict__ hhmin,
    unsigned long long* __restrict__ res, float* __restrict__ outp,
    double* __restrict__ loss_sum) {
  __shared__ unsigned s_live[FBM];
  __shared__ unsigned s_col[FBM];
  __shared__ float wsum[4];

  const int b = blockIdx.x;
  const unsigned nc = counts[b];
  const unsigned long long* myc = cand + (size_t)b * SLOTS;
  const int tid = threadIdx.x;
  const int lane = tid & 63;
  const int wid = tid >> 6;
  const float eps = 0.004f * sqrtf(__uint_as_float(*xnmax) * __uint_as_float(*enmax)) + 0.2f;

  if (tid < FBM) s_live[tid] = 0;
  __syncthreads();

  // phase A: mark live candidates (dd within eps of final hh-min)
  for (unsigned c = tid; c < nc; c += 256) {
    const unsigned long long ent = myc[c];
    const unsigned rc = (unsigned)(ent >> 32);
    const float dd = __uint_as_float((unsigned)(ent & 0xffffffffu));
    const unsigned grow = rc >> 12;
    if (dd <= hhmin[grow] + eps) {
      const unsigned lrow = grow & (FBM - 1);
      atomicAdd(&s_live[lrow], 1u);
      s_col[lrow] = rc & 4095u;   // benign race; only used when live==1
    }
  }
  __syncthreads();

  // init res for multi-candidate rows (block-exclusive rows; syncthreads
  // drains the store before this block's atomics touch it)
  if (tid < FBM && s_live[tid] >= 2) res[b * FBM + tid] = ~0ull;
  __syncthreads();

  // phase B: exact fp32 dot only for multi-candidate rows (wave per cand)
  for (unsigned c = wid; c < nc; c += 4) {
    const unsigned long long ent = myc[c];
    const unsigned rc = (unsigned)(ent >> 32);
    const float dd = __uint_as_float((unsigned)(ent & 0xffffffffu));
    const unsigned grow = rc >> 12;
    if (dd > hhmin[grow] + eps) continue;            // wave-uniform
    const unsigned lrow = grow & (FBM - 1);
    if (s_live[lrow] < 2) continue;                  // single: no dot needed
    const unsigned col = rc & 4095u;
    const float* xp = X + (size_t)grow * D_DIM + lane * 8;
    const float* ep = E + (size_t)col * D_DIM + lane * 8;
    float s = 0.f;
#pragma unroll
    for (int q = 0; q < 2; ++q) {
      const float4 xv = *(const float4*)(xp + q * 4);
      const float4 ev = *(const float4*)(ep + q * 4);
      s += xv.x * ev.x + xv.y * ev.y + xv.z * ev.z + xv.w * ev.w;
    }
#pragma unroll
    for (int m = 32; m >= 1; m >>= 1) s += __shfl_xor(s, m);
    if (lane == 0) {
      const float d = en[col] - 2.f * s + 8192.f;    // positive -> bit-monotone
      const unsigned long long pk =
          ((unsigned long long)__float_as_uint(d) << 32) | col;
      atomicMin(res + grow, pk);                     // ties -> lower col (np)
    }
  }
  __syncthreads();

  // phase C: gather + loss for this block's 128 rows
  float lsum = 0.f;
  const int half = tid >> 7;          // 0..1
  const int c4 = (tid & 127) * 4;
  for (int r0 = 0; r0 < FBM; r0 += 2) {
    const int lrow = r0 + half;
    const int row = b * FBM + lrow;
    const int idx = (s_live[lrow] < 2) ? (int)s_col[lrow]
                                       : (int)(res[row] & 0xfffULL);
    const float4 ev = *(const float4*)(E + (size_t)idx * D_DIM + c4);
    const float4 xv = *(const float4*)(X + (size_t)row * D_DIM + c4);
    *(float4*)(outp + (size_t)row * D_DIM + c4) = ev;
    const float dx = ev.x - xv.x, dy = ev.y - xv.y, dz = ev.z - xv.z, dw = ev.w - xv.w;
    lsum += dx * dx + dy * dy + dz * dz + dw * dw;
  }
#pragma unroll
  for (int m = 32; m >= 1; m >>= 1) lsum += __shfl_xor(lsum, m);
  if (lane == 0) wsum[wid] = lsum;
  __syncthreads();
  if (tid == 0) {
    const double t = (double)wsum[0] + (double)wsum[1] +
                     (double)wsum[2] + (double)wsum[3];
    atomicAdd(loss_sum, t);
  }
}

// ---------------- finalize loss ----------------
__global__ void vq_finalize(const double* __restrict__ loss_sum, float* __restrict__ outp) {
  if (threadIdx.x == 0 && blockIdx.x == 0) {
    outp[(size_t)N_PTS * D_DIM] =
        (float)(1.25 * (*loss_sum) / ((double)N_PTS * (double)D_DIM));
  }
}

// ================= round-2 fallback kernels (ws too small) =================
#define BM 128
#define BN 128
#define NCHUNK 32
#define BK 32
#define NSTEP 16
#define NS (NCHUNK * NSTEP)

__device__ __forceinline__ void cvt_hl(const float4 v, f16x8& H, f16x8& L, const int b) {
  _Float16 h;
  h = (_Float16)v.x; H[b + 0] = h; L[b + 0] = (_Float16)(v.x - (float)h);
  h = (_Float16)v.y; H[b + 1] = h; L[b + 1] = (_Float16)(v.y - (float)h);
  h = (_Float16)v.z; H[b + 2] = h; L[b + 2] = (_Float16)(v.z - (float)h);
  h = (_Float16)v.w; H[b + 3] = h; L[b + 3] = (_Float16)(v.w - (float)h);
}

__global__ void vq_en_only(const float* __restrict__ E, float* __restrict__ en) {
  const int wave = threadIdx.x >> 6;
  const int lane = threadIdx.x & 63;
  const int row = blockIdx.x * 4 + wave;
  const float* src = E + (size_t)row * D_DIM;
  float s = 0.f;
#pragma unroll
  for (int h = 0; h < 2; ++h) {
    float4 v = *(const float4*)(src + h * 256 + lane * 4);
    s += v.x * v.x + v.y * v.y + v.z * v.z + v.w * v.w;
  }
#pragma unroll
  for (int m = 32; m >= 1; m >>= 1) s += __shfl_xor(s, m);
  if (lane == 0) en[row] = s;
}

__global__ __launch_bounds__(256, 2) void vq_main_r2(
    const float* __restrict__ X, const float* __restrict__ E,
    const float* __restrict__ en, float* __restrict__ outp,
    double* __restrict__ loss_sum) {
  __shared__ __align__(16) _Float16 Xh[BM][BK];
  __shared__ __align__(16) _Float16 Xl[BM][BK];
  __shared__ __align__(16) _Float16 Eh[BN][BK];
  __shared__ __align__(16) _Float16 El[BN][BK];
  __shared__ float rval[2][64][2];
  __shared__ int rixd[2][64][2];
  __shared__ int fin_idx[BM];
  __shared__ float wsum[4];

  const int tid = threadIdx.x;
  const int lane = tid & 63;
  const int wid = tid >> 6;
  const int wm = wid >> 1;
  const int wn = wid & 1;
  const int l15 = lane & 15;
  const int lq = lane >> 4;
  const int row0 = blockIdx.x * BM;

  const int srow = tid >> 1;
  const int seg16 = (tid & 1) * 16;
  const float* Xbase = X + (size_t)(row0 + srow) * D_DIM + seg16;

  float4 xgA[4], egA[4], xgB[4], egB[4];
#pragma unroll
  for (int e = 0; e < 4; ++e) xgA[e] = *(const float4*)(Xbase + e * 4);
  {
    const float* ep = E + (size_t)srow * D_DIM + seg16;
#pragma unroll
    for (int e = 0; e < 4; ++e) egA[e] = *(const float4*)(ep + e * 4);
  }

  float minv[16];
  int mini[16];
#pragma unroll
  for (int k = 0; k < 16; ++k) { minv[k] = FLT_MAX; mini[k] = 0; }

  f32x4 acc[4][4];
  float enj[4];

#define STEP(S, XG, EG, XGN, EGN)                                              \
  {                                                                            \
    const int t = (S) & (NSTEP - 1);                                           \
    const int chunk = (S) >> 4;                                                \
    if (t == 0) {                                                              \
      _Pragma("unroll") for (int j = 0; j < 4; ++j)                            \
          enj[j] = en[chunk * BN + wn * 64 + j * 16 + l15];                    \
      _Pragma("unroll") for (int i = 0; i < 4; ++i)                            \
          _Pragma("unroll") for (int j = 0; j < 4; ++j)                        \
              acc[i][j] = (f32x4)(0.f);                                        \
    }                                                                          \
    __syncthreads();                                                           \
    {                                                                          \
      f16x8 H0, H1, L0, L1;                                                    \
      cvt_hl(XG[0], H0, L0, 0); cvt_hl(XG[1], H0, L0, 4);                      \
      cvt_hl(XG[2], H1, L1, 0); cvt_hl(XG[3], H1, L1, 4);                      \
      *(f16x8*)&Xh[srow][seg16] = H0;                                          \
      *(f16x8*)&Xh[srow][seg16 + 8] = H1;                                      \
      *(f16x8*)&Xl[srow][seg16] = L0;                                          \
      *(f16x8*)&Xl[srow][seg16 + 8] = L1;                                      \
      cvt_hl(EG[0], H0, L0, 0); cvt_hl(EG[1], H0, L0, 4);                      \
      cvt_hl(EG[2], H1, L1, 0); cvt_hl(EG[3], H1, L1, 4);                      \
      *(f16x8*)&Eh[srow][seg16] = H0;                                          \
      *(f16x8*)&Eh[srow][seg16 + 8] = H1;                                      \
      *(f16x8*)&El[srow][seg16] = L0;                                          \
      *(f16x8*)&El[srow][seg16 + 8] = L1;                                      \
    }                                                                          \
    if ((S) + 1 < NS) {                                                        \
      const int t1 = ((S) + 1) & (NSTEP - 1);                                  \
      const int c1 = ((S) + 1) >> 4;                                           \
      const float* xp = Xbase + t1 * BK;                                       \
      const float* ep2 = E + (size_t)(c1 * BN + srow) * D_DIM + t1 * BK + seg16; \
      _Pragma("unroll") for (int e = 0; e < 4; ++e)                            \
          XGN[e] = *(const float4*)(xp + e * 4);                               \
      _Pragma("unroll") for (int e = 0; e < 4; ++e)                            \
          EGN[e] = *(const float4*)(ep2 + e * 4);                              \
    }                                                                          \
    __syncthreads();                                                           \
    {                                                                          \
      const int qo = lq * 8;                                                   \
      f16x8 bh[4], bl[4];                                                      \
      _Pragma("unroll") for (int j = 0; j < 4; ++j) {                          \
        bh[j] = *(const f16x8*)&Eh[wn * 64 + j * 16 + l15][qo];                \
        bl[j] = *(const f16x8*)&El[wn * 64 + j * 16 + l15][qo];                \
      }                                                                        \
      _Pragma("unroll") for (int i = 0; i < 4; ++i) {                          \
        const f16x8 ah = *(const f16x8*)&Xh[wm * 64 + i * 16 + l15][qo];       \
        const f16x8 al = *(const f16x8*)&Xl[wm * 64 + i * 16 + l15][qo];       \
        _Pragma("unroll") for (int j = 0; j < 4; ++j) {                        \
          acc[i][j] = __builtin_amdgcn_mfma_f32_16x16x32_f16(ah, bh[j], acc[i][j], 0, 0, 0); \
          acc[i][j] = __builtin_amdgcn_mfma_f32_16x16x32_f16(ah, bl[j], acc[i][j], 0, 0, 0); \
          acc[i][j] = __builtin_amdgcn_mfma_f32_16x16x32_f16(al, bh[j], acc[i][j], 0, 0, 0); \
        }                                                                      \
      }                                                                        \
    }                                                                          \
    if (t == NSTEP - 1) {                                                      \
      _Pragma("unroll") for (int i = 0; i < 4; ++i)                            \
          _Pragma("unroll") for (int j = 0; j < 4; ++j) {                      \
        const int c = chunk * BN + wn * 64 + j * 16 + l15;                     \
        _Pragma("unroll") for (int r = 0; r < 4; ++r) {                        \
          const float dd = fmaf(-2.f, acc[i][j][r], enj[j]);                   \
          const int k = i * 4 + r;                                             \
          if (dd < minv[k]) { minv[k] = dd; mini[k] = c; }                     \
        }                                                                      \
      }                                                                        \
    }                                                                          \
  }

  for (int s = 0; s < NS; s += 2) {
    STEP(s, xgA, egA, xgB, egB);
    STEP(s + 1, xgB, egB, xgA, egA);
  }
#undef STEP

#pragma unroll
  for (int k = 0; k < 16; ++k) {
    float v = minv[k];
    int ix = mini[k];
#pragma unroll
    for (int m = 1; m <= 8; m <<= 1) {
      const float v2 = __shfl_xor(v, m);
      const int ix2 = __shfl_xor(ix, m);
      if (v2 < v || (v2 == v && ix2 < ix)) { v = v2; ix = ix2; }
    }
    if (l15 == 0) {
      const int lrow = (k >> 2) * 16 + lq * 4 + (k & 3);
      rval[wm][lrow][wn] = v;
      rixd[wm][lrow][wn] = ix;
    }
  }
  __syncthreads();
  if (tid < BM) {
    const int wm_ = tid >> 6, lrow = tid & 63;
    const float v0 = rval[wm_][lrow][0], v1 = rval[wm_][lrow][1];
    const int i0 = rixd[wm_][lrow][0], i1 = rixd[wm_][lrow][1];
    fin_idx[tid] = (v1 < v0 || (v1 == v0 && i1 < i0)) ? i1 : i0;
  }
  __syncthreads();

  float lsum = 0.f;
  const int half = tid >> 7;
  const int c4 = (tid & 127) * 4;
  for (int r0 = 0; r0 < BM; r0 += 2) {
    const int r = r0 + half;
    const int idx = fin_idx[r];
    const float4 ev = *(const float4*)(E + (size_t)idx * D_DIM + c4);
    const float4 xv = *(const float4*)(X + (size_t)(row0 + r) * D_DIM + c4);
    *(float4*)(outp + (size_t)(row0 + r) * D_DIM + c4) = ev;
    const float dx = ev.x - xv.x, dy = ev.y - xv.y, dz = ev.z - xv.z, dw = ev.w - xv.w;
    lsum += dx * dx + dy * dy + dz * dz + dw * dw;
  }
#pragma unroll
  for (int m = 32; m >= 1; m >>= 1) lsum += __shfl_xor(lsum, m);
  if (lane == 0) wsum[wid] = lsum;
  __syncthreads();
  if (tid == 0) {
    const double t = (double)wsum[0] + (double)wsum[1] + (double)wsum[2] + (double)wsum[3];
    atomicAdd(loss_sum, t);
  }
}

extern "C" void kernel_launch(void* const* d_in, const int* in_sizes, int n_in,
                              void* d_out, int out_size, void* d_ws, size_t ws_size,
                              hipStream_t stream) {
  const float* X = (const float*)d_in[0];
  const float* E = (const float*)d_in[1];
  float* outp = (float*)d_out;

  // ---- ws layout (fast path) ----
  const size_t off_xpre = 0;
  const size_t sz_xpre = (size_t)4096 * TILE_HB;                 // 64 MB
  const size_t off_epre = off_xpre + sz_xpre;
  const size_t sz_epre = (size_t)256 * TILE_HB;                  // 4 MB
  const size_t off_en = off_epre + sz_epre;                      // 16 KB
  const size_t off_hhmin = off_en + (size_t)K_EMB * 4;           // 256 KB
  const size_t off_res = off_hhmin + (size_t)N_PTS * 4;          // 512 KB
  const size_t off_cand = off_res + (size_t)N_PTS * 8;           // 48 MB
  const size_t off_counts = off_cand + (size_t)NBLK * SLOTS * 8; // 2 KB
  const size_t off_misc = off_counts + NBLK * 4;                 // 32 B
  const size_t need = off_misc + 32;

  if (ws_size >= need) {
    char* ws = (char*)d_ws;
    char* Xpre = ws + off_xpre;
    char* Epre = ws + off_epre;
    float* en = (float*)(ws + off_en);
    float* hhmin = (float*)(ws + off_hhmin);
    unsigned long long* res = (unsigned long long*)(ws + off_res);
    unsigned long long* cand = (unsigned long long*)(ws + off_cand);
    unsigned* counts = (unsigned*)(ws + off_counts);
    unsigned* enmax = (unsigned*)(ws + off_misc);
    unsigned* xnmax = enmax + 1;
    double* loss_sum = (double*)(ws + off_misc + 16);

    (void)hipMemsetAsync(ws + off_misc, 0, 32, stream);   // maxes, loss = 0

    hipLaunchKernelGGL(vq_prep, dim3(272), dim3(256), 0, stream,
                       X, E, Xpre, Epre, en, enmax, xnmax);
    hipLaunchKernelGGL(vq_screen, dim3(NBLK), dim3(256), 0, stream,
                       Xpre, Epre, en, enmax, xnmax, counts, cand, hhmin);
    hipLaunchKernelGGL(vq_resolve, dim3(NBLK), dim3(256), 0, stream,
                       X, E, en, enmax, xnmax, counts, cand, hhmin, res,
                       outp, loss_sum);
    hipLaunchKernelGGL(vq_finalize, dim3(1), dim3(64), 0, stream, loss_sum, outp);
  } else {
    float* en = (float*)d_ws;
    double* loss_sum = (double*)((char*)d_ws + K_EMB * sizeof(float));

    (void)hipMemsetAsync(loss_sum, 0, sizeof(double), stream);
    hipLaunchKernelGGL(vq_en_only, dim3(K_EMB / 4), dim3(256), 0, stream, E, en);
    hipLaunchKernelGGL(vq_main_r2, dim3(N_PTS / BM), dim3(256), 0, stream,
                       X, E, en, outp, loss_sum);
    hipLaunchKernelGGL(vq_finalize, dim3(1), dim3(64), 0, stream, loss_sum, outp);
  }
}

// Round 10
// 588.137 us; speedup vs baseline: 2.0643x; 2.0643x over previous
//
#include <hip/hip_runtime.h>
#include <hip/hip_fp16.h>
#include <float.h>

typedef _Float16 f16x8 __attribute__((ext_vector_type(8)));
typedef float f32x4 __attribute__((ext_vector_type(4)));

#define N_PTS 65536
#define D_DIM 512
#define K_EMB 4096

// ---------- screen geometry (r8-proven config) ----------
#define FBM 256            // rows per screen block
#define FBN 256            // cols per chunk
#define NCH 16             // K_EMB / FBN
#define NDS 16             // D_DIM / 32
#define NT  256            // NCH * NDS steps
#define NBLK 256           // N_PTS / FBM
#define TILE_HB 16384      // 16KB per 256-row hi-tile
#define SLOTS 24576u       // candidate slots per 256-row block

#define GLOAD16(gsrc, ldst)                                                    \
  __builtin_amdgcn_global_load_lds(                                            \
      (const __attribute__((address_space(1))) void*)(gsrc),                   \
      (__attribute__((address_space(3))) void*)(ldst), 16, 0, 0)

#define BAR() asm volatile("s_barrier" ::: "memory")
#define VMCNT(n) asm volatile("s_waitcnt vmcnt(" #n ")" ::: "memory")
#define PRIO(n) __builtin_amdgcn_s_setprio(n)

// ---------------- Kernel 1: fused norms + fp16-hi tile precompute -----------
// bid 0..255: X super-tile (256 rows); bid 256..271: E super-tile.
// Tile layout (16KB per 256-row x 32-half tile): element (row=rg*16+l15,
// k=kq*8+h) at byte ((rg*4+kq)*16 + l15)*16 + h*2.
__global__ void vq_prep(const float* __restrict__ X, const float* __restrict__ E,
                        char* __restrict__ Xpre, char* __restrict__ Epre,
                        float* __restrict__ en, unsigned* __restrict__ enmax,
                        unsigned* __restrict__ xnmax) {
  __shared__ float smax[4];
  const int bid = blockIdx.x;
  const int r = threadIdx.x;
  const int lane = r & 63;
  const int wid = r >> 6;
  const bool isX = bid < 256;
  const float* src = isX ? X + ((size_t)bid * 256 + r) * D_DIM
                         : E + ((size_t)(bid - 256) * 256 + r) * D_DIM;
  char* dstb = isX ? Xpre + (size_t)bid * 16 * TILE_HB
                   : Epre + (size_t)(bid - 256) * 16 * TILE_HB;
  const int rg = r >> 4, l15 = r & 15;
  float nrm = 0.f;
#pragma unroll 4
  for (int ds = 0; ds < 16; ++ds) {
    const float* base = src + ds * 32;
    char* dst = dstb + (size_t)ds * TILE_HB;
#pragma unroll
    for (int kq = 0; kq < 4; ++kq) {
      const float4 a = *(const float4*)(base + kq * 8);
      const float4 b = *(const float4*)(base + kq * 8 + 4);
      nrm += a.x * a.x + a.y * a.y + a.z * a.z + a.w * a.w +
             b.x * b.x + b.y * b.y + b.z * b.z + b.w * b.w;
      f16x8 H;
      H[0] = (_Float16)a.x; H[1] = (_Float16)a.y; H[2] = (_Float16)a.z; H[3] = (_Float16)a.w;
      H[4] = (_Float16)b.x; H[5] = (_Float16)b.y; H[6] = (_Float16)b.z; H[7] = (_Float16)b.w;
      *(f16x8*)(dst + ((size_t)((rg * 4 + kq) * 16 + l15)) * 16) = H;
    }
  }
  if (!isX) en[(bid - 256) * 256 + r] = nrm;
  float mx = nrm;
#pragma unroll
  for (int m = 32; m >= 1; m >>= 1) mx = fmaxf(mx, __shfl_xor(mx, m));
  if (lane == 0) smax[wid] = mx;
  __syncthreads();
  if (r == 0) {
    const float mm = fmaxf(fmaxf(smax[0], smax[1]), fmaxf(smax[2], smax[3]));
    atomicMax(isX ? xnmax : enmax, __float_as_uint(mm));
  }
}

// ---------------- Kernel 2: hh screen GEMM (r8 config, verbatim) ------------
__global__ __launch_bounds__(512, 1) void vq_screen(
    const char* __restrict__ Xpre, const char* __restrict__ Epre,
    const float* __restrict__ en, const unsigned* __restrict__ enmax,
    const unsigned* __restrict__ xnmax, unsigned* __restrict__ counts,
    unsigned long long* __restrict__ cand, float* __restrict__ hhmin) {
  __shared__ __align__(16) char bufX[2][16384];
  __shared__ __align__(16) char bufE[2][16384];
  __shared__ __align__(16) float en_lds[K_EMB];
  __shared__ float argv_[2][FBM];
  __shared__ unsigned s_cnt;

  const int tid = threadIdx.x;
  const int lane = tid & 63;
  const int wid = tid >> 6;
  const int wm = wid >> 1;   // 0..3: 64-row group
  const int wn = wid & 1;    // 0..1: 128-col group
  const int l15 = lane & 15;
  const int lq = lane >> 4;
  const int mt = blockIdx.x;

  unsigned long long* myc = cand + (size_t)mt * SLOTS;
  if (tid == 0) s_cnt = 0;

  const float eps = 0.004f * sqrtf(__uint_as_float(*xnmax) * __uint_as_float(*enmax)) + 0.2f;

#define STAGE_X(g1)                                                            \
  {                                                                            \
    const char* s_ = Xpre + ((size_t)(mt * 16 + ((g1) & 15))) * TILE_HB +      \
                     wid * 2048 + lane * 16;                                   \
    char* d_ = &bufX[(g1) & 1][wid * 2048];                                    \
    GLOAD16(s_, d_); GLOAD16(s_ + 1024, d_ + 1024);                            \
  }
#define STAGE_E(g1)                                                            \
  {                                                                            \
    const char* s_ = Epre + ((size_t)(g1)) * TILE_HB + wid * 2048 + lane * 16; \
    char* d_ = &bufE[(g1) & 1][wid * 2048];                                    \
    GLOAD16(s_, d_); GLOAD16(s_ + 1024, d_ + 1024);                            \
  }

  // prologue: en table + step-0 tiles; full drain + barrier (also publishes
  // s_cnt=0 to all waves)
  {
    const char* s_ = (const char*)en + wid * 2048 + lane * 16;
    char* d_ = (char*)en_lds + wid * 2048;
    GLOAD16(s_, d_); GLOAD16(s_ + 1024, d_ + 1024);
  }
  STAGE_X(0);
  STAGE_E(0);
  VMCNT(0);
  BAR();

  f32x4 acc[4][8];
  float minv[16];
#pragma unroll
  for (int k = 0; k < 16; ++k) minv[k] = FLT_MAX;

  f16x8 AH[4], BH[8];

  for (int g = 0; g < NT; ++g) {
    const char* XB = &bufX[g & 1][0];
    const char* EB = &bufE[g & 1][0];

    if ((g & 15) == 0) {
#pragma unroll
      for (int i = 0; i < 4; ++i)
#pragma unroll
        for (int j = 0; j < 8; ++j) acc[i][j] = (f32x4)(0.f);
    }

    // ---- P1: prefetch X(g+1); counted drain; read AH + BH[0..3]; 16 MFMA ---
    if (g + 1 < NT) { STAGE_X(g + 1); VMCNT(2); } else { VMCNT(0); }
    BAR();
#pragma unroll
    for (int i = 0; i < 4; ++i)
      AH[i] = *(const f16x8*)(XB + (wm * 4 + i) * 1024 + lane * 16);
#pragma unroll
    for (int j = 0; j < 4; ++j)
      BH[j] = *(const f16x8*)(EB + (wn * 8 + j) * 1024 + lane * 16);
    PRIO(1);
#pragma unroll
    for (int i = 0; i < 4; ++i)
#pragma unroll
      for (int j = 0; j < 4; ++j)
        acc[i][j] = __builtin_amdgcn_mfma_f32_16x16x32_f16(AH[i], BH[j], acc[i][j], 0, 0, 0);
    PRIO(0);

    // ---- P2: prefetch E(g+1); read BH[4..7]; 16 MFMA ----------------------
    if (g + 1 < NT) STAGE_E(g + 1);
    BAR();
#pragma unroll
    for (int j = 4; j < 8; ++j)
      BH[j] = *(const f16x8*)(EB + (wn * 8 + j) * 1024 + lane * 16);
    PRIO(1);
#pragma unroll
    for (int i = 0; i < 4; ++i)
#pragma unroll
      for (int j = 4; j < 8; ++j)
        acc[i][j] = __builtin_amdgcn_mfma_f32_16x16x32_f16(AH[i], BH[j], acc[i][j], 0, 0, 0);
    PRIO(0);

    // ---- chunk end: row-min update + candidate emission (LDS counter) -----
    if ((g & 15) == 15) {
      const int c = g >> 4;
      float ej[8];
#pragma unroll
      for (int j = 0; j < 8; ++j)
        ej[j] = en_lds[c * 256 + wn * 128 + j * 16 + l15];
#pragma unroll
      for (int k = 0; k < 16; ++k) {
        const int i = k >> 2, r = k & 3;
        float dd[8];
        float cm = FLT_MAX;
#pragma unroll
        for (int j = 0; j < 8; ++j) {
          dd[j] = fmaf(-2.f, acc[i][j][r], ej[j]);
          cm = fminf(cm, dd[j]);
        }
#pragma unroll
        for (int m = 1; m <= 8; m <<= 1) cm = fminf(cm, __shfl_xor(cm, m));
        minv[k] = fminf(minv[k], cm);
        const float thr = minv[k] + eps;
        const unsigned grow = (unsigned)(mt * FBM + wm * 64 + i * 16 + lq * 4 + r);
#pragma unroll
        for (int j = 0; j < 8; ++j) {
          if (dd[j] <= thr) {
            const unsigned slot = atomicAdd(&s_cnt, 1u);  // LDS atomic: fast
            if (slot < SLOTS) {
              const unsigned col = (unsigned)(c * 256 + wn * 128 + j * 16 + l15);
              myc[slot] = ((unsigned long long)((grow << 12) | col) << 32) |
                          __float_as_uint(dd[j]);
            }
          }
        }
      }
    }
  }
#undef STAGE_X
#undef STAGE_E

  // ---- epilogue: per-row final hh-min + count -----------------------------
#pragma unroll
  for (int k = 0; k < 16; ++k) {
    if (l15 == 0)
      argv_[wn][wm * 64 + (k >> 2) * 16 + lq * 4 + (k & 3)] = minv[k];
  }
  __syncthreads();
  if (tid < FBM)
    hhmin[mt * FBM + tid] = fminf(argv_[0][tid], argv_[1][tid]);
  if (tid == 0)
    counts[mt] = (s_cnt < SLOTS) ? s_cnt : SLOTS;
}

// ---------------- Kernel 3: fused resolve (filter + exact dots + gather) ----
// Block b owns rows b*256..b*256+255 exclusively (candidates are block-local).
__global__ __launch_bounds__(512) void vq_resolve(
    const float* __restrict__ X, const float* __restrict__ E,
    const float* __restrict__ en, const unsigned* __restrict__ enmax,
    const unsigned* __restrict__ xnmax, const unsigned* __restrict__ counts,
    const unsigned long long* __restrict__ cand, const float* __restrict__ hhmin,
    unsigned long long* __restrict__ res, float* __restrict__ outp,
    double* __restrict__ loss_sum) {
  __shared__ unsigned s_live[FBM];
  __shared__ unsigned s_col[FBM];
  __shared__ float wsum[8];

  const int b = blockIdx.x;
  const unsigned nc = counts[b];
  const unsigned long long* myc = cand + (size_t)b * SLOTS;
  const int tid = threadIdx.x;
  const int lane = tid & 63;
  const int wid = tid >> 6;
  const float eps = 0.004f * sqrtf(__uint_as_float(*xnmax) * __uint_as_float(*enmax)) + 0.2f;

  if (tid < FBM) s_live[tid] = 0;
  __syncthreads();

  // phase A: mark live candidates (dd within eps of final hh-min)
  for (unsigned c = tid; c < nc; c += 512) {
    const unsigned long long ent = myc[c];
    const unsigned rc = (unsigned)(ent >> 32);
    const float dd = __uint_as_float((unsigned)(ent & 0xffffffffu));
    const unsigned grow = rc >> 12;
    if (dd <= hhmin[grow] + eps) {
      const unsigned lrow = grow & (FBM - 1);
      atomicAdd(&s_live[lrow], 1u);
      s_col[lrow] = rc & 4095u;   // benign race; only used when live==1
    }
  }
  __syncthreads();

  // init res for multi-candidate rows (block-exclusive rows; syncthreads
  // drains the store before this block's atomics touch it)
  if (tid < FBM && s_live[tid] >= 2) res[b * FBM + tid] = ~0ull;
  __syncthreads();

  // phase B: exact fp32 dot only for multi-candidate rows (wave per cand)
  for (unsigned c = wid; c < nc; c += 8) {
    const unsigned long long ent = myc[c];
    const unsigned rc = (unsigned)(ent >> 32);
    const float dd = __uint_as_float((unsigned)(ent & 0xffffffffu));
    const unsigned grow = rc >> 12;
    if (dd > hhmin[grow] + eps) continue;            // wave-uniform
    const unsigned lrow = grow & (FBM - 1);
    if (s_live[lrow] < 2) continue;                  // single: no dot needed
    const unsigned col = rc & 4095u;
    const float* xp = X + (size_t)grow * D_DIM + lane * 8;
    const float* ep = E + (size_t)col * D_DIM + lane * 8;
    float s = 0.f;
#pragma unroll
    for (int q = 0; q < 2; ++q) {
      const float4 xv = *(const float4*)(xp + q * 4);
      const float4 ev = *(const float4*)(ep + q * 4);
      s += xv.x * ev.x + xv.y * ev.y + xv.z * ev.z + xv.w * ev.w;
    }
#pragma unroll
    for (int m = 32; m >= 1; m >>= 1) s += __shfl_xor(s, m);
    if (lane == 0) {
      const float d = en[col] - 2.f * s + 8192.f;    // positive -> bit-monotone
      const unsigned long long pk =
          ((unsigned long long)__float_as_uint(d) << 32) | col;
      atomicMin(res + grow, pk);                     // ties -> lower col (np)
    }
  }
  __syncthreads();

  // phase C: gather + loss for this block's 256 rows
  float lsum = 0.f;
  const int sub = tid >> 7;           // 0..3
  const int c4 = (tid & 127) * 4;
  for (int r0 = 0; r0 < FBM; r0 += 4) {
    const int lrow = r0 + sub;
    const int row = b * FBM + lrow;
    const int idx = (s_live[lrow] < 2) ? (int)s_col[lrow]
                                       : (int)(res[row] & 0xfffULL);
    const float4 ev = *(const float4*)(E + (size_t)idx * D_DIM + c4);
    const float4 xv = *(const float4*)(X + (size_t)row * D_DIM + c4);
    *(float4*)(outp + (size_t)row * D_DIM + c4) = ev;
    const float dx = ev.x - xv.x, dy = ev.y - xv.y, dz = ev.z - xv.z, dw = ev.w - xv.w;
    lsum += dx * dx + dy * dy + dz * dz + dw * dw;
  }
#pragma unroll
  for (int m = 32; m >= 1; m >>= 1) lsum += __shfl_xor(lsum, m);
  if (lane == 0) wsum[wid] = lsum;
  __syncthreads();
  if (tid == 0) {
    double t = 0.0;
#pragma unroll
    for (int w = 0; w < 8; ++w) t += (double)wsum[w];
    atomicAdd(loss_sum, t);
  }
}

// ---------------- finalize loss ----------------
__global__ void vq_finalize(const double* __restrict__ loss_sum, float* __restrict__ outp) {
  if (threadIdx.x == 0 && blockIdx.x == 0) {
    outp[(size_t)N_PTS * D_DIM] =
        (float)(1.25 * (*loss_sum) / ((double)N_PTS * (double)D_DIM));
  }
}

// ================= round-2 fallback kernels (ws too small) =================
#define BM 128
#define BN 128
#define NCHUNK 32
#define BK 32
#define NSTEP 16
#define NS (NCHUNK * NSTEP)

__device__ __forceinline__ void cvt_hl(const float4 v, f16x8& H, f16x8& L, const int b) {
  _Float16 h;
  h = (_Float16)v.x; H[b + 0] = h; L[b + 0] = (_Float16)(v.x - (float)h);
  h = (_Float16)v.y; H[b + 1] = h; L[b + 1] = (_Float16)(v.y - (float)h);
  h = (_Float16)v.z; H[b + 2] = h; L[b + 2] = (_Float16)(v.z - (float)h);
  h = (_Float16)v.w; H[b + 3] = h; L[b + 3] = (_Float16)(v.w - (float)h);
}

__global__ void vq_en_only(const float* __restrict__ E, float* __restrict__ en) {
  const int wave = threadIdx.x >> 6;
  const int lane = threadIdx.x & 63;
  const int row = blockIdx.x * 4 + wave;
  const float* src = E + (size_t)row * D_DIM;
  float s = 0.f;
#pragma unroll
  for (int h = 0; h < 2; ++h) {
    float4 v = *(const float4*)(src + h * 256 + lane * 4);
    s += v.x * v.x + v.y * v.y + v.z * v.z + v.w * v.w;
  }
#pragma unroll
  for (int m = 32; m >= 1; m >>= 1) s += __shfl_xor(s, m);
  if (lane == 0) en[row] = s;
}

__global__ __launch_bounds__(256, 2) void vq_main_r2(
    const float* __restrict__ X, const float* __restrict__ E,
    const float* __restrict__ en, float* __restrict__ outp,
    double* __restrict__ loss_sum) {
  __shared__ __align__(16) _Float16 Xh[BM][BK];
  __shared__ __align__(16) _Float16 Xl[BM][BK];
  __shared__ __align__(16) _Float16 Eh[BN][BK];
  __shared__ __align__(16) _Float16 El[BN][BK];
  __shared__ float rval[2][64][2];
  __shared__ int rixd[2][64][2];
  __shared__ int fin_idx[BM];
  __shared__ float wsum[4];

  const int tid = threadIdx.x;
  const int lane = tid & 63;
  const int wid = tid >> 6;
  const int wm = wid >> 1;
  const int wn = wid & 1;
  const int l15 = lane & 15;
  const int lq = lane >> 4;
  const int row0 = blockIdx.x * BM;

  const int srow = tid >> 1;
  const int seg16 = (tid & 1) * 16;
  const float* Xbase = X + (size_t)(row0 + srow) * D_DIM + seg16;

  float4 xgA[4], egA[4], xgB[4], egB[4];
#pragma unroll
  for (int e = 0; e < 4; ++e) xgA[e] = *(const float4*)(Xbase + e * 4);
  {
    const float* ep = E + (size_t)srow * D_DIM + seg16;
#pragma unroll
    for (int e = 0; e < 4; ++e) egA[e] = *(const float4*)(ep + e * 4);
  }

  float minv[16];
  int mini[16];
#pragma unroll
  for (int k = 0; k < 16; ++k) { minv[k] = FLT_MAX; mini[k] = 0; }

  f32x4 acc[4][4];
  float enj[4];

#define STEP(S, XG, EG, XGN, EGN)                                              \
  {                                                                            \
    const int t = (S) & (NSTEP - 1);                                           \
    const int chunk = (S) >> 4;                                                \
    if (t == 0) {                                                              \
      _Pragma("unroll") for (int j = 0; j < 4; ++j)                            \
          enj[j] = en[chunk * BN + wn * 64 + j * 16 + l15];                    \
      _Pragma("unroll") for (int i = 0; i < 4; ++i)                            \
          _Pragma("unroll") for (int j = 0; j < 4; ++j)                        \
              acc[i][j] = (f32x4)(0.f);                                        \
    }                                                                          \
    __syncthreads();                                                           \
    {                                                                          \
      f16x8 H0, H1, L0, L1;                                                    \
      cvt_hl(XG[0], H0, L0, 0); cvt_hl(XG[1], H0, L0, 4);                      \
      cvt_hl(XG[2], H1, L1, 0); cvt_hl(XG[3], H1, L1, 4);                      \
      *(f16x8*)&Xh[srow][seg16] = H0;                                          \
      *(f16x8*)&Xh[srow][seg16 + 8] = H1;                                      \
      *(f16x8*)&Xl[srow][seg16] = L0;                                          \
      *(f16x8*)&Xl[srow][seg16 + 8] = L1;                                      \
      cvt_hl(EG[0], H0, L0, 0); cvt_hl(EG[1], H0, L0, 4);                      \
      cvt_hl(EG[2], H1, L1, 0); cvt_hl(EG[3], H1, L1, 4);                      \
      *(f16x8*)&Eh[srow][seg16] = H0;                                          \
      *(f16x8*)&Eh[srow][seg16 + 8] = H1;                                      \
      *(f16x8*)&El[srow][seg16] = L0;                                          \
      *(f16x8*)&El[srow][seg16 + 8] = L1;                                      \
    }                                                                          \
    if ((S) + 1 < NS) {                                                        \
      const int t1 = ((S) + 1) & (NSTEP - 1);                                  \
      const int c1 = ((S) + 1) >> 4;                                           \
      const float* xp = Xbase + t1 * BK;                                       \
      const float* ep2 = E + (size_t)(c1 * BN + srow) * D_DIM + t1 * BK + seg16; \
      _Pragma("unroll") for (int e = 0; e < 4; ++e)                            \
          XGN[e] = *(const float4*)(xp + e * 4);                               \
      _Pragma("unroll") for (int e = 0; e < 4; ++e)                            \
          EGN[e] = *(const float4*)(ep2 + e * 4);                              \
    }                                                                          \
    __syncthreads();                                                           \
    {                                                                          \
      const int qo = lq * 8;                                                   \
      f16x8 bh[4], bl[4];                                                      \
      _Pragma("unroll") for (int j = 0; j < 4; ++j) {                          \
        bh[j] = *(const f16x8*)&Eh[wn * 64 + j * 16 + l15][qo];                \
        bl[j] = *(const f16x8*)&El[wn * 64 + j * 16 + l15][qo];                \
      }                                                                        \
      _Pragma("unroll") for (int i = 0; i < 4; ++i) {                          \
        const f16x8 ah = *(const f16x8*)&Xh[wm * 64 + i * 16 + l15][qo];       \
        const f16x8 al = *(const f16x8*)&Xl[wm * 64 + i * 16 + l15][qo];       \
        _Pragma("unroll") for (int j = 0; j < 4; ++j) {                        \
          acc[i][j] = __builtin_amdgcn_mfma_f32_16x16x32_f16(ah, bh[j], acc[i][j], 0, 0, 0); \
          acc[i][j] = __builtin_amdgcn_mfma_f32_16x16x32_f16(ah, bl[j], acc[i][j], 0, 0, 0); \
          acc[i][j] = __builtin_amdgcn_mfma_f32_16x16x32_f16(al, bh[j], acc[i][j], 0, 0, 0); \
        }                                                                      \
      }                                                                        \
    }                                                                          \
    if (t == NSTEP - 1) {                                                      \
      _Pragma("unroll") for (int i = 0; i < 4; ++i)                            \
          _Pragma("unroll") for (int j = 0; j < 4; ++j) {                      \
        const int c = chunk * BN + wn * 64 + j * 16 + l15;                     \
        _Pragma("unroll") for (int r = 0; r < 4; ++r) {                        \
          const float dd = fmaf(-2.f, acc[i][j][r], enj[j]);                   \
          const int k = i * 4 + r;                                             \
          if (dd < minv[k]) { minv[k] = dd; mini[k] = c; }                     \
        }                                                                      \
      }                                                                        \
    }                                                                          \
  }

  for (int s = 0; s < NS; s += 2) {
    STEP(s, xgA, egA, xgB, egB);
    STEP(s + 1, xgB, egB, xgA, egA);
  }
#undef STEP

#pragma unroll
  for (int k = 0; k < 16; ++k) {
    float v = minv[k];
    int ix = mini[k];
#pragma unroll
    for (int m = 1; m <= 8; m <<= 1) {
      const float v2 = __shfl_xor(v, m);
      const int ix2 = __shfl_xor(ix, m);
      if (v2 < v || (v2 == v && ix2 < ix)) { v = v2; ix = ix2; }
    }
    if (l15 == 0) {
      const int lrow = (k >> 2) * 16 + lq * 4 + (k & 3);
      rval[wm][lrow][wn] = v;
      rixd[wm][lrow][wn] = ix;
    }
  }
  __syncthreads();
  if (tid < BM) {
    const int wm_ = tid >> 6, lrow = tid & 63;
    const float v0 = rval[wm_][lrow][0], v1 = rval[wm_][lrow][1];
    const int i0 = rixd[wm_][lrow][0], i1 = rixd[wm_][lrow][1];
    fin_idx[tid] = (v1 < v0 || (v1 == v0 && i1 < i0)) ? i1 : i0;
  }
  __syncthreads();

  float lsum = 0.f;
  const int half = tid >> 7;
  const int c4 = (tid & 127) * 4;
  for (int r0 = 0; r0 < BM; r0 += 2) {
    const int r = r0 + half;
    const int idx = fin_idx[r];
    const float4 ev = *(const float4*)(E + (size_t)idx * D_DIM + c4);
    const float4 xv = *(const float4*)(X + (size_t)(row0 + r) * D_DIM + c4);
    *(float4*)(outp + (size_t)(row0 + r) * D_DIM + c4) = ev;
    const float dx = ev.x - xv.x, dy = ev.y - xv.y, dz = ev.z - xv.z, dw = ev.w - xv.w;
    lsum += dx * dx + dy * dy + dz * dz + dw * dw;
  }
#pragma unroll
  for (int m = 32; m >= 1; m >>= 1) lsum += __shfl_xor(lsum, m);
  if (lane == 0) wsum[wid] = lsum;
  __syncthreads();
  if (tid == 0) {
    const double t = (double)wsum[0] + (double)wsum[1] + (double)wsum[2] + (double)wsum[3];
    atomicAdd(loss_sum, t);
  }
}

extern "C" void kernel_launch(void* const* d_in, const int* in_sizes, int n_in,
                              void* d_out, int out_size, void* d_ws, size_t ws_size,
                              hipStream_t stream) {
  const float* X = (const float*)d_in[0];
  const float* E = (const float*)d_in[1];
  float* outp = (float*)d_out;

  // ---- ws layout (fast path) ----
  const size_t off_xpre = 0;
  const size_t sz_xpre = (size_t)4096 * TILE_HB;                 // 64 MB
  const size_t off_epre = off_xpre + sz_xpre;
  const size_t sz_epre = (size_t)256 * TILE_HB;                  // 4 MB
  const size_t off_en = off_epre + sz_epre;                      // 16 KB
  const size_t off_hhmin = off_en + (size_t)K_EMB * 4;           // 256 KB
  const size_t off_res = off_hhmin + (size_t)N_PTS * 4;          // 512 KB
  const size_t off_cand = off_res + (size_t)N_PTS * 8;           // 48 MB
  const size_t off_counts = off_cand + (size_t)NBLK * SLOTS * 8; // 1 KB
  const size_t off_misc = off_counts + NBLK * 4;                 // 32 B
  const size_t need = off_misc + 32;

  if (ws_size >= need) {
    char* ws = (char*)d_ws;
    char* Xpre = ws + off_xpre;
    char* Epre = ws + off_epre;
    float* en = (float*)(ws + off_en);
    float* hhmin = (float*)(ws + off_hhmin);
    unsigned long long* res = (unsigned long long*)(ws + off_res);
    unsigned long long* cand = (unsigned long long*)(ws + off_cand);
    unsigned* counts = (unsigned*)(ws + off_counts);
    unsigned* enmax = (unsigned*)(ws + off_misc);
    unsigned* xnmax = enmax + 1;
    double* loss_sum = (double*)(ws + off_misc + 16);

    (void)hipMemsetAsync(ws + off_misc, 0, 32, stream);   // maxes, loss = 0

    hipLaunchKernelGGL(vq_prep, dim3(272), dim3(256), 0, stream,
                       X, E, Xpre, Epre, en, enmax, xnmax);
    hipLaunchKernelGGL(vq_screen, dim3(NBLK), dim3(512), 0, stream,
                       Xpre, Epre, en, enmax, xnmax, counts, cand, hhmin);
    hipLaunchKernelGGL(vq_resolve, dim3(NBLK), dim3(512), 0, stream,
                       X, E, en, enmax, xnmax, counts, cand, hhmin, res,
                       outp, loss_sum);
    hipLaunchKernelGGL(vq_finalize, dim3(1), dim3(64), 0, stream, loss_sum, outp);
  } else {
    float* en = (float*)d_ws;
    double* loss_sum = (double*)((char*)d_ws + K_EMB * sizeof(float));

    (void)hipMemsetAsync(loss_sum, 0, sizeof(double), stream);
    hipLaunchKernelGGL(vq_en_only, dim3(K_EMB / 4), dim3(256), 0, stream, E, en);
    hipLaunchKernelGGL(vq_main_r2, dim3(N_PTS / BM), dim3(256), 0, stream,
                       X, E, en, outp, loss_sum);
    hipLaunchKernelGGL(vq_finalize, dim3(1), dim3(64), 0, stream, loss_sum, outp);
  }
}

// Round 11
// 513.955 us; speedup vs baseline: 2.3622x; 1.1443x over previous
//
#include <hip/hip_runtime.h>
#include <hip/hip_fp16.h>
#include <float.h>

typedef _Float16 f16x8 __attribute__((ext_vector_type(8)));
typedef float f32x4 __attribute__((ext_vector_type(4)));

#define N_PTS 65536
#define D_DIM 512
#define K_EMB 4096

// ---------- screen geometry ----------
#define FBM 256            // rows per screen block
#define FBN 256            // cols per chunk
#define NCH 16             // K_EMB / FBN
#define NTS 128            // steps (BK=64 halves per step)
#define NBLK 256           // N_PTS / FBM
#define TILE_HB 16384      // 16KB per 256-row x 32-half tile
#define SLOTS 24576u       // candidate slots per 256-row block

#define GLOAD16(gsrc, ldst)                                                    \
  __builtin_amdgcn_global_load_lds(                                            \
      (const __attribute__((address_space(1))) void*)(gsrc),                   \
      (__attribute__((address_space(3))) void*)(ldst), 16, 0, 0)

#define BAR() asm volatile("s_barrier" ::: "memory")
#define VMCNT(n) asm volatile("s_waitcnt vmcnt(" #n ")" ::: "memory")
#define PRIO(n) __builtin_amdgcn_s_setprio(n)

// ---------------- Kernel 1: fused norms + fp16-hi tiles (balanced, grid 256) -
// Block b: X supertile b (256 rows, thread=row) + E rows [b*16, b*16+16)
// (thread = (row = tid>>4, ds = tid&15)). Tile layout: element
// (row=rg*16+l15, k=kq*8+h) at byte ((rg*4+kq)*16 + l15)*16 + h*2.
__global__ __launch_bounds__(256) void vq_prep(
    const float* __restrict__ X, const float* __restrict__ E,
    char* __restrict__ Xpre, char* __restrict__ Epre,
    float* __restrict__ en, unsigned* __restrict__ enmax,
    unsigned* __restrict__ xnmax) {
  __shared__ float smax[8];
  const int b = blockIdx.x;
  const int tid = threadIdx.x;
  const int lane = tid & 63;
  const int wid = tid >> 6;

  // ---- X supertile ----
  {
    const float* src = X + ((size_t)b * 256 + tid) * D_DIM;
    char* dstb = Xpre + (size_t)b * 16 * TILE_HB;
    const int rg = tid >> 4, l15 = tid & 15;
    float nrm = 0.f;
#pragma unroll 4
    for (int ds = 0; ds < 16; ++ds) {
      const float* base = src + ds * 32;
      char* dst = dstb + (size_t)ds * TILE_HB;
#pragma unroll
      for (int kq = 0; kq < 4; ++kq) {
        const float4 a = *(const float4*)(base + kq * 8);
        const float4 c = *(const float4*)(base + kq * 8 + 4);
        nrm += a.x * a.x + a.y * a.y + a.z * a.z + a.w * a.w +
               c.x * c.x + c.y * c.y + c.z * c.z + c.w * c.w;
        f16x8 H;
        H[0] = (_Float16)a.x; H[1] = (_Float16)a.y; H[2] = (_Float16)a.z; H[3] = (_Float16)a.w;
        H[4] = (_Float16)c.x; H[5] = (_Float16)c.y; H[6] = (_Float16)c.z; H[7] = (_Float16)c.w;
        *(f16x8*)(dst + ((size_t)((rg * 4 + kq) * 16 + l15)) * 16) = H;
      }
    }
    float mx = nrm;
#pragma unroll
    for (int m = 32; m >= 1; m >>= 1) mx = fmaxf(mx, __shfl_xor(mx, m));
    if (lane == 0) smax[wid] = mx;
  }

  // ---- E rows b*16 .. b*16+15 ----
  {
    const int erow = b * 16 + (tid >> 4);
    const int ds = tid & 15;
    const float* base = E + (size_t)erow * D_DIM + ds * 32;
    const int st = erow >> 8, r2 = erow & 255;
    const int rg2 = r2 >> 4, l152 = r2 & 15;
    char* dst = Epre + ((size_t)(st * 16 + ds)) * TILE_HB;
    float enrm = 0.f;
#pragma unroll
    for (int kq = 0; kq < 4; ++kq) {
      const float4 a = *(const float4*)(base + kq * 8);
      const float4 c = *(const float4*)(base + kq * 8 + 4);
      enrm += a.x * a.x + a.y * a.y + a.z * a.z + a.w * a.w +
              c.x * c.x + c.y * c.y + c.z * c.z + c.w * c.w;
      f16x8 H;
      H[0] = (_Float16)a.x; H[1] = (_Float16)a.y; H[2] = (_Float16)a.z; H[3] = (_Float16)a.w;
      H[4] = (_Float16)c.x; H[5] = (_Float16)c.y; H[6] = (_Float16)c.z; H[7] = (_Float16)c.w;
      *(f16x8*)(dst + ((size_t)((rg2 * 4 + kq) * 16 + l152)) * 16) = H;
    }
    // sum partials across the 16 lanes of this row (butterfly: all lanes get it)
#pragma unroll
    for (int m = 1; m <= 8; m <<= 1) enrm += __shfl_xor(enrm, m);
    if (ds == 0) en[erow] = enrm;
    float emx = enrm;
#pragma unroll
    for (int m = 32; m >= 1; m >>= 1) emx = fmaxf(emx, __shfl_xor(emx, m));
    if (lane == 0) smax[4 + wid] = emx;
  }
  __syncthreads();
  if (tid == 0) {
    const float xm = fmaxf(fmaxf(smax[0], smax[1]), fmaxf(smax[2], smax[3]));
    const float em = fmaxf(fmaxf(smax[4], smax[5]), fmaxf(smax[6], smax[7]));
    atomicMax(xnmax, __float_as_uint(xm));
    atomicMax(enmax, __float_as_uint(em));
  }
}

// ---------------- Kernel 2: hh screen GEMM, BK=64 (half the barriers) -------
__global__ __launch_bounds__(512, 1) void vq_screen(
    const char* __restrict__ Xpre, const char* __restrict__ Epre,
    const float* __restrict__ en, const unsigned* __restrict__ enmax,
    const unsigned* __restrict__ xnmax, unsigned* __restrict__ counts,
    unsigned long long* __restrict__ cand, float* __restrict__ hhmin) {
  __shared__ __align__(16) char bufX[2][32768];
  __shared__ __align__(16) char bufE[2][32768];
  __shared__ __align__(16) float en_lds[K_EMB];
  __shared__ float argv_[2][FBM];
  __shared__ unsigned s_cnt;

  const int tid = threadIdx.x;
  const int lane = tid & 63;
  const int wid = tid >> 6;
  const int wm = wid >> 1;   // 0..3: 64-row group
  const int wn = wid & 1;    // 0..1: 128-col group
  const int l15 = lane & 15;
  const int lq = lane >> 4;
  const int mt = blockIdx.x;

  unsigned long long* myc = cand + (size_t)mt * SLOTS;
  if (tid == 0) s_cnt = 0;

  const float eps = 0.004f * sqrtf(__uint_as_float(*xnmax) * __uint_as_float(*enmax)) + 0.2f;

  // step g covers k = g*64 .. g*64+63: X tiles mt*16 + (g&7)*2, +1 (contiguous
  // 32KB); E tiles 2g, 2g+1 (contiguous 32KB).
#define STAGE_X2(g1)                                                           \
  {                                                                            \
    const char* s_ = Xpre + ((size_t)(mt * 16 + ((g1) & 7) * 2)) * TILE_HB +   \
                     wid * 4096 + lane * 16;                                   \
    char* d_ = &bufX[(g1) & 1][wid * 4096];                                    \
    GLOAD16(s_, d_); GLOAD16(s_ + 1024, d_ + 1024);                            \
    GLOAD16(s_ + 2048, d_ + 2048); GLOAD16(s_ + 3072, d_ + 3072);              \
  }
#define STAGE_E2(g1)                                                           \
  {                                                                            \
    const char* s_ = Epre + ((size_t)(g1) * 2) * TILE_HB + wid * 4096 + lane * 16; \
    char* d_ = &bufE[(g1) & 1][wid * 4096];                                    \
    GLOAD16(s_, d_); GLOAD16(s_ + 1024, d_ + 1024);                            \
    GLOAD16(s_ + 2048, d_ + 2048); GLOAD16(s_ + 3072, d_ + 3072);              \
  }

  // prologue: en table + step-0 tiles; full drain + barrier (also publishes
  // s_cnt=0 to all waves)
  {
    const char* s_ = (const char*)en + wid * 2048 + lane * 16;
    char* d_ = (char*)en_lds + wid * 2048;
    GLOAD16(s_, d_); GLOAD16(s_ + 1024, d_ + 1024);
  }
  STAGE_X2(0);
  STAGE_E2(0);
  VMCNT(0);
  BAR();

  f32x4 acc[4][8];
  float minv[16];
#pragma unroll
  for (int k = 0; k < 16; ++k) minv[k] = FLT_MAX;

  f16x8 AH[8], BH[8];

  for (int g = 0; g < NTS; ++g) {
    const char* XB = &bufX[g & 1][0];
    const char* EB = &bufE[g & 1][0];

    if ((g & 7) == 0) {
#pragma unroll
      for (int i = 0; i < 4; ++i)
#pragma unroll
        for (int j = 0; j < 8; ++j) acc[i][j] = (f32x4)(0.f);
    }

    // ---- P1: prefetch X(g+1); counted drain (leaves X(g+1) in flight);
    //          read AH (both k-halves) + BH[j0..3]; 32 MFMA -----------------
    if (g + 1 < NTS) { STAGE_X2(g + 1); VMCNT(4); } else { VMCNT(0); }
    BAR();
#pragma unroll
    for (int h = 0; h < 2; ++h)
#pragma unroll
      for (int i = 0; i < 4; ++i)
        AH[h * 4 + i] = *(const f16x8*)(XB + h * 16384 + (wm * 4 + i) * 1024 + lane * 16);
#pragma unroll
    for (int h = 0; h < 2; ++h)
#pragma unroll
      for (int j = 0; j < 4; ++j)
        BH[h * 4 + j] = *(const f16x8*)(EB + h * 16384 + (wn * 8 + j) * 1024 + lane * 16);
    PRIO(1);
#pragma unroll
    for (int i = 0; i < 4; ++i)
#pragma unroll
      for (int j = 0; j < 4; ++j) {
        acc[i][j] = __builtin_amdgcn_mfma_f32_16x16x32_f16(AH[i], BH[j], acc[i][j], 0, 0, 0);
        acc[i][j] = __builtin_amdgcn_mfma_f32_16x16x32_f16(AH[4 + i], BH[4 + j], acc[i][j], 0, 0, 0);
      }
    PRIO(0);

    // ---- P2: prefetch E(g+1); read BH[j4..7] (both k-halves); 32 MFMA ------
    if (g + 1 < NTS) STAGE_E2(g + 1);
    BAR();
#pragma unroll
    for (int h = 0; h < 2; ++h)
#pragma unroll
      for (int j = 0; j < 4; ++j)
        BH[h * 4 + j] = *(const f16x8*)(EB + h * 16384 + (wn * 8 + 4 + j) * 1024 + lane * 16);
    PRIO(1);
#pragma unroll
    for (int i = 0; i < 4; ++i)
#pragma unroll
      for (int j = 0; j < 4; ++j) {
        acc[i][4 + j] = __builtin_amdgcn_mfma_f32_16x16x32_f16(AH[i], BH[j], acc[i][4 + j], 0, 0, 0);
        acc[i][4 + j] = __builtin_amdgcn_mfma_f32_16x16x32_f16(AH[4 + i], BH[4 + j], acc[i][4 + j], 0, 0, 0);
      }
    PRIO(0);

    // ---- chunk end (8 steps = 512 k): row-min + candidate emission --------
    if ((g & 7) == 7) {
      const int c = g >> 3;
      float ej[8];
#pragma unroll
      for (int j = 0; j < 8; ++j)
        ej[j] = en_lds[c * 256 + wn * 128 + j * 16 + l15];
#pragma unroll
      for (int k = 0; k < 16; ++k) {
        const int i = k >> 2, r = k & 3;
        float dd[8];
        float cm = FLT_MAX;
#pragma unroll
        for (int j = 0; j < 8; ++j) {
          dd[j] = fmaf(-2.f, acc[i][j][r], ej[j]);
          cm = fminf(cm, dd[j]);
        }
#pragma unroll
        for (int m = 1; m <= 8; m <<= 1) cm = fminf(cm, __shfl_xor(cm, m));
        minv[k] = fminf(minv[k], cm);
        const float thr = minv[k] + eps;
        const unsigned grow = (unsigned)(mt * FBM + wm * 64 + i * 16 + lq * 4 + r);
#pragma unroll
        for (int j = 0; j < 8; ++j) {
          if (dd[j] <= thr) {
            const unsigned slot = atomicAdd(&s_cnt, 1u);  // LDS atomic: fast
            if (slot < SLOTS) {
              const unsigned col = (unsigned)(c * 256 + wn * 128 + j * 16 + l15);
              myc[slot] = ((unsigned long long)((grow << 12) | col) << 32) |
                          __float_as_uint(dd[j]);
            }
          }
        }
      }
    }
  }
#undef STAGE_X2
#undef STAGE_E2

  // ---- epilogue: per-row final hh-min + count -----------------------------
#pragma unroll
  for (int k = 0; k < 16; ++k) {
    if (l15 == 0)
      argv_[wn][wm * 64 + (k >> 2) * 16 + lq * 4 + (k & 3)] = minv[k];
  }
  __syncthreads();
  if (tid < FBM)
    hhmin[mt * FBM + tid] = fminf(argv_[0][tid], argv_[1][tid]);
  if (tid == 0)
    counts[mt] = (s_cnt < SLOTS) ? s_cnt : SLOTS;
}

// ---------------- Kernel 3: fused resolve (filter + exact dots + gather) ----
// Block b owns rows b*256..b*256+255 exclusively (candidates are block-local).
__global__ __launch_bounds__(512) void vq_resolve(
    const float* __restrict__ X, const float* __restrict__ E,
    const float* __restrict__ en, const unsigned* __restrict__ enmax,
    const unsigned* __restrict__ xnmax, const unsigned* __restrict__ counts,
    const unsigned long long* __restrict__ cand, const float* __restrict__ hhmin,
    unsigned long long* __restrict__ res, float* __restrict__ outp,
    double* __restrict__ loss_sum) {
  __shared__ unsigned s_live[FBM];
  __shared__ unsigned s_col[FBM];
  __shared__ float wsum[8];

  const int b = blockIdx.x;
  const unsigned nc = counts[b];
  const unsigned long long* myc = cand + (size_t)b * SLOTS;
  const int tid = threadIdx.x;
  const int lane = tid & 63;
  const int wid = tid >> 6;
  const float eps = 0.004f * sqrtf(__uint_as_float(*xnmax) * __uint_as_float(*enmax)) + 0.2f;

  if (tid < FBM) s_live[tid] = 0;
  __syncthreads();

  // phase A: mark live candidates (dd within eps of final hh-min)
  for (unsigned c = tid; c < nc; c += 512) {
    const unsigned long long ent = myc[c];
    const unsigned rc = (unsigned)(ent >> 32);
    const float dd = __uint_as_float((unsigned)(ent & 0xffffffffu));
    const unsigned grow = rc >> 12;
    if (dd <= hhmin[grow] + eps) {
      const unsigned lrow = grow & (FBM - 1);
      atomicAdd(&s_live[lrow], 1u);
      s_col[lrow] = rc & 4095u;   // benign race; only used when live==1
    }
  }
  __syncthreads();

  // init res for multi-candidate rows (block-exclusive rows)
  if (tid < FBM && s_live[tid] >= 2) res[b * FBM + tid] = ~0ull;
  __syncthreads();

  // phase B: exact fp32 dot only for multi-candidate rows (wave per cand)
  for (unsigned c = wid; c < nc; c += 8) {
    const unsigned long long ent = myc[c];
    const unsigned rc = (unsigned)(ent >> 32);
    const float dd = __uint_as_float((unsigned)(ent & 0xffffffffu));
    const unsigned grow = rc >> 12;
    if (dd > hhmin[grow] + eps) continue;            // wave-uniform
    const unsigned lrow = grow & (FBM - 1);
    if (s_live[lrow] < 2) continue;                  // single: no dot needed
    const unsigned col = rc & 4095u;
    const float* xp = X + (size_t)grow * D_DIM + lane * 8;
    const float* ep = E + (size_t)col * D_DIM + lane * 8;
    float s = 0.f;
#pragma unroll
    for (int q = 0; q < 2; ++q) {
      const float4 xv = *(const float4*)(xp + q * 4);
      const float4 ev = *(const float4*)(ep + q * 4);
      s += xv.x * ev.x + xv.y * ev.y + xv.z * ev.z + xv.w * ev.w;
    }
#pragma unroll
    for (int m = 32; m >= 1; m >>= 1) s += __shfl_xor(s, m);
    if (lane == 0) {
      const float d = en[col] - 2.f * s + 8192.f;    // positive -> bit-monotone
      const unsigned long long pk =
          ((unsigned long long)__float_as_uint(d) << 32) | col;
      atomicMin(res + grow, pk);                     // ties -> lower col (np)
    }
  }
  __syncthreads();

  // phase C: gather + loss for this block's 256 rows
  float lsum = 0.f;
  const int sub = tid >> 7;           // 0..3
  const int c4 = (tid & 127) * 4;
  for (int r0 = 0; r0 < FBM; r0 += 4) {
    const int lrow = r0 + sub;
    const int row = b * FBM + lrow;
    const int idx = (s_live[lrow] < 2) ? (int)s_col[lrow]
                                       : (int)(res[row] & 0xfffULL);
    const float4 ev = *(const float4*)(E + (size_t)idx * D_DIM + c4);
    const float4 xv = *(const float4*)(X + (size_t)row * D_DIM + c4);
    *(float4*)(outp + (size_t)row * D_DIM + c4) = ev;
    const float dx = ev.x - xv.x, dy = ev.y - xv.y, dz = ev.z - xv.z, dw = ev.w - xv.w;
    lsum += dx * dx + dy * dy + dz * dz + dw * dw;
  }
#pragma unroll
  for (int m = 32; m >= 1; m >>= 1) lsum += __shfl_xor(lsum, m);
  if (lane == 0) wsum[wid] = lsum;
  __syncthreads();
  if (tid == 0) {
    double t = 0.0;
#pragma unroll
    for (int w = 0; w < 8; ++w) t += (double)wsum[w];
    atomicAdd(loss_sum, t);
  }
}

// ---------------- finalize loss ----------------
__global__ void vq_finalize(const double* __restrict__ loss_sum, float* __restrict__ outp) {
  if (threadIdx.x == 0 && blockIdx.x == 0) {
    outp[(size_t)N_PTS * D_DIM] =
        (float)(1.25 * (*loss_sum) / ((double)N_PTS * (double)D_DIM));
  }
}

// ================= round-2 fallback kernels (ws too small) =================
#define BM 128
#define BN 128
#define NCHUNK 32
#define BK 32
#define NSTEP 16
#define NS (NCHUNK * NSTEP)

__device__ __forceinline__ void cvt_hl(const float4 v, f16x8& H, f16x8& L, const int b) {
  _Float16 h;
  h = (_Float16)v.x; H[b + 0] = h; L[b + 0] = (_Float16)(v.x - (float)h);
  h = (_Float16)v.y; H[b + 1] = h; L[b + 1] = (_Float16)(v.y - (float)h);
  h = (_Float16)v.z; H[b + 2] = h; L[b + 2] = (_Float16)(v.z - (float)h);
  h = (_Float16)v.w; H[b + 3] = h; L[b + 3] = (_Float16)(v.w - (float)h);
}

__global__ void vq_en_only(const float* __restrict__ E, float* __restrict__ en) {
  const int wave = threadIdx.x >> 6;
  const int lane = threadIdx.x & 63;
  const int row = blockIdx.x * 4 + wave;
  const float* src = E + (size_t)row * D_DIM;
  float s = 0.f;
#pragma unroll
  for (int h = 0; h < 2; ++h) {
    float4 v = *(const float4*)(src + h * 256 + lane * 4);
    s += v.x * v.x + v.y * v.y + v.z * v.z + v.w * v.w;
  }
#pragma unroll
  for (int m = 32; m >= 1; m >>= 1) s += __shfl_xor(s, m);
  if (lane == 0) en[row] = s;
}

__global__ __launch_bounds__(256, 2) void vq_main_r2(
    const float* __restrict__ X, const float* __restrict__ E,
    const float* __restrict__ en, float* __restrict__ outp,
    double* __restrict__ loss_sum) {
  __shared__ __align__(16) _Float16 Xh[BM][BK];
  __shared__ __align__(16) _Float16 Xl[BM][BK];
  __shared__ __align__(16) _Float16 Eh[BN][BK];
  __shared__ __align__(16) _Float16 El[BN][BK];
  __shared__ float rval[2][64][2];
  __shared__ int rixd[2][64][2];
  __shared__ int fin_idx[BM];
  __shared__ float wsum[4];

  const int tid = threadIdx.x;
  const int lane = tid & 63;
  const int wid = tid >> 6;
  const int wm = wid >> 1;
  const int wn = wid & 1;
  const int l15 = lane & 15;
  const int lq = lane >> 4;
  const int row0 = blockIdx.x * BM;

  const int srow = tid >> 1;
  const int seg16 = (tid & 1) * 16;
  const float* Xbase = X + (size_t)(row0 + srow) * D_DIM + seg16;

  float4 xgA[4], egA[4], xgB[4], egB[4];
#pragma unroll
  for (int e = 0; e < 4; ++e) xgA[e] = *(const float4*)(Xbase + e * 4);
  {
    const float* ep = E + (size_t)srow * D_DIM + seg16;
#pragma unroll
    for (int e = 0; e < 4; ++e) egA[e] = *(const float4*)(ep + e * 4);
  }

  float minv[16];
  int mini[16];
#pragma unroll
  for (int k = 0; k < 16; ++k) { minv[k] = FLT_MAX; mini[k] = 0; }

  f32x4 acc[4][4];
  float enj[4];

#define STEP(S, XG, EG, XGN, EGN)                                              \
  {                                                                            \
    const int t = (S) & (NSTEP - 1);                                           \
    const int chunk = (S) >> 4;                                                \
    if (t == 0) {                                                              \
      _Pragma("unroll") for (int j = 0; j < 4; ++j)                            \
          enj[j] = en[chunk * BN + wn * 64 + j * 16 + l15];                    \
      _Pragma("unroll") for (int i = 0; i < 4; ++i)                            \
          _Pragma("unroll") for (int j = 0; j < 4; ++j)                        \
              acc[i][j] = (f32x4)(0.f);                                        \
    }                                                                          \
    __syncthreads();                                                           \
    {                                                                          \
      f16x8 H0, H1, L0, L1;                                                    \
      cvt_hl(XG[0], H0, L0, 0); cvt_hl(XG[1], H0, L0, 4);                      \
      cvt_hl(XG[2], H1, L1, 0); cvt_hl(XG[3], H1, L1, 4);                      \
      *(f16x8*)&Xh[srow][seg16] = H0;                                          \
      *(f16x8*)&Xh[srow][seg16 + 8] = H1;                                      \
      *(f16x8*)&Xl[srow][seg16] = L0;                                          \
      *(f16x8*)&Xl[srow][seg16 + 8] = L1;                                      \
      cvt_hl(EG[0], H0, L0, 0); cvt_hl(EG[1], H0, L0, 4);                      \
      cvt_hl(EG[2], H1, L1, 0); cvt_hl(EG[3], H1, L1, 4);                      \
      *(f16x8*)&Eh[srow][seg16] = H0;                                          \
      *(f16x8*)&Eh[srow][seg16 + 8] = H1;                                      \
      *(f16x8*)&El[srow][seg16] = L0;                                          \
      *(f16x8*)&El[srow][seg16 + 8] = L1;                                      \
    }                                                                          \
    if ((S) + 1 < NS) {                                                        \
      const int t1 = ((S) + 1) & (NSTEP - 1);                                  \
      const int c1 = ((S) + 1) >> 4;                                           \
      const float* xp = Xbase + t1 * BK;                                       \
      const float* ep2 = E + (size_t)(c1 * BN + srow) * D_DIM + t1 * BK + seg16; \
      _Pragma("unroll") for (int e = 0; e < 4; ++e)                            \
          XGN[e] = *(const float4*)(xp + e * 4);                               \
      _Pragma("unroll") for (int e = 0; e < 4; ++e)                            \
          EGN[e] = *(const float4*)(ep2 + e * 4);                              \
    }                                                                          \
    __syncthreads();                                                           \
    {                                                                          \
      const int qo = lq * 8;                                                   \
      f16x8 bh[4], bl[4];                                                      \
      _Pragma("unroll") for (int j = 0; j < 4; ++j) {                          \
        bh[j] = *(const f16x8*)&Eh[wn * 64 + j * 16 + l15][qo];                \
        bl[j] = *(const f16x8*)&El[wn * 64 + j * 16 + l15][qo];                \
      }                                                                        \
      _Pragma("unroll") for (int i = 0; i < 4; ++i) {                          \
        const f16x8 ah = *(const f16x8*)&Xh[wm * 64 + i * 16 + l15][qo];       \
        const f16x8 al = *(const f16x8*)&Xl[wm * 64 + i * 16 + l15][qo];       \
        _Pragma("unroll") for (int j = 0; j < 4; ++j) {                        \
          acc[i][j] = __builtin_amdgcn_mfma_f32_16x16x32_f16(ah, bh[j], acc[i][j], 0, 0, 0); \
          acc[i][j] = __builtin_amdgcn_mfma_f32_16x16x32_f16(ah, bl[j], acc[i][j], 0, 0, 0); \
          acc[i][j] = __builtin_amdgcn_mfma_f32_16x16x32_f16(al, bh[j], acc[i][j], 0, 0, 0); \
        }                                                                      \
      }                                                                        \
    }                                                                          \
    if (t == NSTEP - 1) {                                                      \
      _Pragma("unroll") for (int i = 0; i < 4; ++i)                            \
          _Pragma("unroll") for (int j = 0; j < 4; ++j) {                      \
        const int c = chunk * BN + wn * 64 + j * 16 + l15;                     \
        _Pragma("unroll") for (int r = 0; r < 4; ++r) {                        \
          const float dd = fmaf(-2.f, acc[i][j][r], enj[j]);                   \
          const int k = i * 4 + r;                                             \
          if (dd < minv[k]) { minv[k] = dd; mini[k] = c; }                     \
        }                                                                      \
      }                                                                        \
    }                                                                          \
  }

  for (int s = 0; s < NS; s += 2) {
    STEP(s, xgA, egA, xgB, egB);
    STEP(s + 1, xgB, egB, xgA, egA);
  }
#undef STEP

#pragma unroll
  for (int k = 0; k < 16; ++k) {
    float v = minv[k];
    int ix = mini[k];
#pragma unroll
    for (int m = 1; m <= 8; m <<= 1) {
      const float v2 = __shfl_xor(v, m);
      const int ix2 = __shfl_xor(ix, m);
      if (v2 < v || (v2 == v && ix2 < ix)) { v = v2; ix = ix2; }
    }
    if (l15 == 0) {
      const int lrow = (k >> 2) * 16 + lq * 4 + (k & 3);
      rval[wm][lrow][wn] = v;
      rixd[wm][lrow][wn] = ix;
    }
  }
  __syncthreads();
  if (tid < BM) {
    const int wm_ = tid >> 6, lrow = tid & 63;
    const float v0 = rval[wm_][lrow][0], v1 = rval[wm_][lrow][1];
    const int i0 = rixd[wm_][lrow][0], i1 = rixd[wm_][lrow][1];
    fin_idx[tid] = (v1 < v0 || (v1 == v0 && i1 < i0)) ? i1 : i0;
  }
  __syncthreads();

  float lsum = 0.f;
  const int half = tid >> 7;
  const int c4 = (tid & 127) * 4;
  for (int r0 = 0; r0 < BM; r0 += 2) {
    const int r = r0 + half;
    const int idx = fin_idx[r];
    const float4 ev = *(const float4*)(E + (size_t)idx * D_DIM + c4);
    const float4 xv = *(const float4*)(X + (size_t)(row0 + r) * D_DIM + c4);
    *(float4*)(outp + (size_t)(row0 + r) * D_DIM + c4) = ev;
    const float dx = ev.x - xv.x, dy = ev.y - xv.y, dz = ev.z - xv.z, dw = ev.w - xv.w;
    lsum += dx * dx + dy * dy + dz * dz + dw * dw;
  }
#pragma unroll
  for (int m = 32; m >= 1; m >>= 1) lsum += __shfl_xor(lsum, m);
  if (lane == 0) wsum[wid] = lsum;
  __syncthreads();
  if (tid == 0) {
    const double t = (double)wsum[0] + (double)wsum[1] + (double)wsum[2] + (double)wsum[3];
    atomicAdd(loss_sum, t);
  }
}

extern "C" void kernel_launch(void* const* d_in, const int* in_sizes, int n_in,
                              void* d_out, int out_size, void* d_ws, size_t ws_size,
                              hipStream_t stream) {
  const float* X = (const float*)d_in[0];
  const float* E = (const float*)d_in[1];
  float* outp = (float*)d_out;

  // ---- ws layout (fast path) ----
  const size_t off_xpre = 0;
  const size_t sz_xpre = (size_t)4096 * TILE_HB;                 // 64 MB
  const size_t off_epre = off_xpre + sz_xpre;
  const size_t sz_epre = (size_t)256 * TILE_HB;                  // 4 MB
  const size_t off_en = off_epre + sz_epre;                      // 16 KB
  const size_t off_hhmin = off_en + (size_t)K_EMB * 4;           // 256 KB
  const size_t off_res = off_hhmin + (size_t)N_PTS * 4;          // 512 KB
  const size_t off_cand = off_res + (size_t)N_PTS * 8;           // 48 MB
  const size_t off_counts = off_cand + (size_t)NBLK * SLOTS * 8; // 1 KB
  const size_t off_misc = off_counts + NBLK * 4;                 // 32 B
  const size_t need = off_misc + 32;

  if (ws_size >= need) {
    char* ws = (char*)d_ws;
    char* Xpre = ws + off_xpre;
    char* Epre = ws + off_epre;
    float* en = (float*)(ws + off_en);
    float* hhmin = (float*)(ws + off_hhmin);
    unsigned long long* res = (unsigned long long*)(ws + off_res);
    unsigned long long* cand = (unsigned long long*)(ws + off_cand);
    unsigned* counts = (unsigned*)(ws + off_counts);
    unsigned* enmax = (unsigned*)(ws + off_misc);
    unsigned* xnmax = enmax + 1;
    double* loss_sum = (double*)(ws + off_misc + 16);

    (void)hipMemsetAsync(ws + off_misc, 0, 32, stream);   // maxes, loss = 0

    hipLaunchKernelGGL(vq_prep, dim3(256), dim3(256), 0, stream,
                       X, E, Xpre, Epre, en, enmax, xnmax);
    hipLaunchKernelGGL(vq_screen, dim3(NBLK), dim3(512), 0, stream,
                       Xpre, Epre, en, enmax, xnmax, counts, cand, hhmin);
    hipLaunchKernelGGL(vq_resolve, dim3(NBLK), dim3(512), 0, stream,
                       X, E, en, enmax, xnmax, counts, cand, hhmin, res,
                       outp, loss_sum);
    hipLaunchKernelGGL(vq_finalize, dim3(1), dim3(64), 0, stream, loss_sum, outp);
  } else {
    float* en = (float*)d_ws;
    double* loss_sum = (double*)((char*)d_ws + K_EMB * sizeof(float));

    (void)hipMemsetAsync(loss_sum, 0, sizeof(double), stream);
    hipLaunchKernelGGL(vq_en_only, dim3(K_EMB / 4), dim3(256), 0, stream, E, en);
    hipLaunchKernelGGL(vq_main_r2, dim3(N_PTS / BM), dim3(256), 0, stream,
                       X, E, en, outp, loss_sum);
    hipLaunchKernelGGL(vq_finalize, dim3(1), dim3(64), 0, stream, loss_sum, outp);
  }
}

// Round 12
// 486.018 us; speedup vs baseline: 2.4980x; 1.0575x over previous
//
#include <hip/hip_runtime.h>
#include <hip/hip_fp16.h>
#include <float.h>

typedef _Float16 f16x8 __attribute__((ext_vector_type(8)));
typedef float f32x4 __attribute__((ext_vector_type(4)));

#define N_PTS 65536
#define D_DIM 512
#define K_EMB 4096

// ---------- screen geometry ----------
#define FBM 256            // rows per screen block
#define FBN 256            // cols per chunk
#define NCH 16             // K_EMB / FBN
#define NTS 128            // steps (BK=64 halves per step)
#define NBLK 256           // N_PTS / FBM
#define TILE_HB 16384      // 16KB per 256-row x 32-half tile
#define SLOTS 24576u       // candidate slots per 256-row block

#define GLOAD16(gsrc, ldst)                                                    \
  __builtin_amdgcn_global_load_lds(                                            \
      (const __attribute__((address_space(1))) void*)(gsrc),                   \
      (__attribute__((address_space(3))) void*)(ldst), 16, 0, 0)

#define BAR() asm volatile("s_barrier" ::: "memory")
#define VMCNT(n) asm volatile("s_waitcnt vmcnt(" #n ")" ::: "memory")
#define PRIO(n) __builtin_amdgcn_s_setprio(n)

__device__ __forceinline__ void lds_min_u64(unsigned long long* p,
                                            unsigned long long v) {
  unsigned long long old = *p;
  while (v < old) {
    const unsigned long long seen = atomicCAS(p, old, v);
    if (seen == old) break;
    old = seen;
  }
}

// ---------------- Kernel 1: fused norms + fp16-hi tiles (balanced, grid 256) -
// Block b: X supertile b (256 rows, thread=row) + E rows [b*16, b*16+16)
// (thread = (row = tid>>4, ds = tid&15)). Tile layout: element
// (row=rg*16+l15, k=kq*8+h) at byte ((rg*4+kq)*16 + l15)*16 + h*2.
__global__ __launch_bounds__(256) void vq_prep(
    const float* __restrict__ X, const float* __restrict__ E,
    char* __restrict__ Xpre, char* __restrict__ Epre,
    float* __restrict__ en, unsigned* __restrict__ enmax,
    unsigned* __restrict__ xnmax) {
  __shared__ float smax[8];
  const int b = blockIdx.x;
  const int tid = threadIdx.x;
  const int lane = tid & 63;
  const int wid = tid >> 6;

  // ---- X supertile ----
  {
    const float* src = X + ((size_t)b * 256 + tid) * D_DIM;
    char* dstb = Xpre + (size_t)b * 16 * TILE_HB;
    const int rg = tid >> 4, l15 = tid & 15;
    float nrm = 0.f;
#pragma unroll 4
    for (int ds = 0; ds < 16; ++ds) {
      const float* base = src + ds * 32;
      char* dst = dstb + (size_t)ds * TILE_HB;
#pragma unroll
      for (int kq = 0; kq < 4; ++kq) {
        const float4 a = *(const float4*)(base + kq * 8);
        const float4 c = *(const float4*)(base + kq * 8 + 4);
        nrm += a.x * a.x + a.y * a.y + a.z * a.z + a.w * a.w +
               c.x * c.x + c.y * c.y + c.z * c.z + c.w * c.w;
        f16x8 H;
        H[0] = (_Float16)a.x; H[1] = (_Float16)a.y; H[2] = (_Float16)a.z; H[3] = (_Float16)a.w;
        H[4] = (_Float16)c.x; H[5] = (_Float16)c.y; H[6] = (_Float16)c.z; H[7] = (_Float16)c.w;
        *(f16x8*)(dst + ((size_t)((rg * 4 + kq) * 16 + l15)) * 16) = H;
      }
    }
    float mx = nrm;
#pragma unroll
    for (int m = 32; m >= 1; m >>= 1) mx = fmaxf(mx, __shfl_xor(mx, m));
    if (lane == 0) smax[wid] = mx;
  }

  // ---- E rows b*16 .. b*16+15 ----
  {
    const int erow = b * 16 + (tid >> 4);
    const int ds = tid & 15;
    const float* base = E + (size_t)erow * D_DIM + ds * 32;
    const int st = erow >> 8, r2 = erow & 255;
    const int rg2 = r2 >> 4, l152 = r2 & 15;
    char* dst = Epre + ((size_t)(st * 16 + ds)) * TILE_HB;
    float enrm = 0.f;
#pragma unroll
    for (int kq = 0; kq < 4; ++kq) {
      const float4 a = *(const float4*)(base + kq * 8);
      const float4 c = *(const float4*)(base + kq * 8 + 4);
      enrm += a.x * a.x + a.y * a.y + a.z * a.z + a.w * a.w +
              c.x * c.x + c.y * c.y + c.z * c.z + c.w * c.w;
      f16x8 H;
      H[0] = (_Float16)a.x; H[1] = (_Float16)a.y; H[2] = (_Float16)a.z; H[3] = (_Float16)a.w;
      H[4] = (_Float16)c.x; H[5] = (_Float16)c.y; H[6] = (_Float16)c.z; H[7] = (_Float16)c.w;
      *(f16x8*)(dst + ((size_t)((rg2 * 4 + kq) * 16 + l152)) * 16) = H;
    }
#pragma unroll
    for (int m = 1; m <= 8; m <<= 1) enrm += __shfl_xor(enrm, m);
    if (ds == 0) en[erow] = enrm;
    float emx = enrm;
#pragma unroll
    for (int m = 32; m >= 1; m >>= 1) emx = fmaxf(emx, __shfl_xor(emx, m));
    if (lane == 0) smax[4 + wid] = emx;
  }
  __syncthreads();
  if (tid == 0) {
    const float xm = fmaxf(fmaxf(smax[0], smax[1]), fmaxf(smax[2], smax[3]));
    const float em = fmaxf(fmaxf(smax[4], smax[5]), fmaxf(smax[6], smax[7]));
    atomicMax(xnmax, __float_as_uint(xm));
    atomicMax(enmax, __float_as_uint(em));
  }
}

// ---------------- Kernel 2: hh screen GEMM (BK=64) + fused resolve ----------
__global__ __launch_bounds__(512, 1) void vq_screen(
    const char* __restrict__ Xpre, const char* __restrict__ Epre,
    const float* __restrict__ en, const unsigned* __restrict__ enmax,
    const unsigned* __restrict__ xnmax, unsigned long long* __restrict__ cand,
    const float* __restrict__ X, const float* __restrict__ E,
    float* __restrict__ outp, double* __restrict__ loss_sum) {
  __shared__ __align__(16) char bufX[2][32768];
  __shared__ __align__(16) char bufE[2][32768];
  __shared__ __align__(16) float en_lds[K_EMB];
  __shared__ float argv_[2][FBM];
  __shared__ unsigned s_cnt;

  const int tid = threadIdx.x;
  const int lane = tid & 63;
  const int wid = tid >> 6;
  const int wm = wid >> 1;   // 0..3: 64-row group
  const int wn = wid & 1;    // 0..1: 128-col group
  const int l15 = lane & 15;
  const int lq = lane >> 4;
  const int mt = blockIdx.x;

  unsigned long long* myc = cand + (size_t)mt * SLOTS;
  if (tid == 0) s_cnt = 0;

  const float eps = 0.004f * sqrtf(__uint_as_float(*xnmax) * __uint_as_float(*enmax)) + 0.2f;

  // step g covers k = g*64 .. g*64+63: X tiles mt*16 + (g&7)*2, +1; E tiles 2g, 2g+1.
#define STAGE_X2(g1)                                                           \
  {                                                                            \
    const char* s_ = Xpre + ((size_t)(mt * 16 + ((g1) & 7) * 2)) * TILE_HB +   \
                     wid * 4096 + lane * 16;                                   \
    char* d_ = &bufX[(g1) & 1][wid * 4096];                                    \
    GLOAD16(s_, d_); GLOAD16(s_ + 1024, d_ + 1024);                            \
    GLOAD16(s_ + 2048, d_ + 2048); GLOAD16(s_ + 3072, d_ + 3072);              \
  }
#define STAGE_E2(g1)                                                           \
  {                                                                            \
    const char* s_ = Epre + ((size_t)(g1) * 2) * TILE_HB + wid * 4096 + lane * 16; \
    char* d_ = &bufE[(g1) & 1][wid * 4096];                                    \
    GLOAD16(s_, d_); GLOAD16(s_ + 1024, d_ + 1024);                            \
    GLOAD16(s_ + 2048, d_ + 2048); GLOAD16(s_ + 3072, d_ + 3072);              \
  }

  // prologue: en table + step-0 tiles; full drain + barrier (also publishes s_cnt=0)
  {
    const char* s_ = (const char*)en + wid * 2048 + lane * 16;
    char* d_ = (char*)en_lds + wid * 2048;
    GLOAD16(s_, d_); GLOAD16(s_ + 1024, d_ + 1024);
  }
  STAGE_X2(0);
  STAGE_E2(0);
  VMCNT(0);
  BAR();

  f32x4 acc[4][8];
  float minv[16];
#pragma unroll
  for (int k = 0; k < 16; ++k) minv[k] = FLT_MAX;

  f16x8 AH[8], BH[8];

  for (int g = 0; g < NTS; ++g) {
    const char* XB = &bufX[g & 1][0];
    const char* EB = &bufE[g & 1][0];

    if ((g & 7) == 0) {
#pragma unroll
      for (int i = 0; i < 4; ++i)
#pragma unroll
        for (int j = 0; j < 8; ++j) acc[i][j] = (f32x4)(0.f);
    }

    // ---- P1: prefetch X(g+1); counted drain; read AH + BH[j0..3]; 32 MFMA --
    if (g + 1 < NTS) { STAGE_X2(g + 1); VMCNT(4); } else { VMCNT(0); }
    BAR();
#pragma unroll
    for (int h = 0; h < 2; ++h)
#pragma unroll
      for (int i = 0; i < 4; ++i)
        AH[h * 4 + i] = *(const f16x8*)(XB + h * 16384 + (wm * 4 + i) * 1024 + lane * 16);
#pragma unroll
    for (int h = 0; h < 2; ++h)
#pragma unroll
      for (int j = 0; j < 4; ++j)
        BH[h * 4 + j] = *(const f16x8*)(EB + h * 16384 + (wn * 8 + j) * 1024 + lane * 16);
    PRIO(1);
#pragma unroll
    for (int i = 0; i < 4; ++i)
#pragma unroll
      for (int j = 0; j < 4; ++j) {
        acc[i][j] = __builtin_amdgcn_mfma_f32_16x16x32_f16(AH[i], BH[j], acc[i][j], 0, 0, 0);
        acc[i][j] = __builtin_amdgcn_mfma_f32_16x16x32_f16(AH[4 + i], BH[4 + j], acc[i][j], 0, 0, 0);
      }
    PRIO(0);

    // ---- P2: prefetch E(g+1); read BH[j4..7]; 32 MFMA ----------------------
    if (g + 1 < NTS) STAGE_E2(g + 1);
    BAR();
#pragma unroll
    for (int h = 0; h < 2; ++h)
#pragma unroll
      for (int j = 0; j < 4; ++j)
        BH[h * 4 + j] = *(const f16x8*)(EB + h * 16384 + (wn * 8 + 4 + j) * 1024 + lane * 16);
    PRIO(1);
#pragma unroll
    for (int i = 0; i < 4; ++i)
#pragma unroll
      for (int j = 0; j < 4; ++j) {
        acc[i][4 + j] = __builtin_amdgcn_mfma_f32_16x16x32_f16(AH[i], BH[j], acc[i][4 + j], 0, 0, 0);
        acc[i][4 + j] = __builtin_amdgcn_mfma_f32_16x16x32_f16(AH[4 + i], BH[4 + j], acc[i][4 + j], 0, 0, 0);
      }
    PRIO(0);

    // ---- chunk end (8 steps = 512 k): row-min + candidate emission --------
    if ((g & 7) == 7) {
      const int c = g >> 3;
      float ej[8];
#pragma unroll
      for (int j = 0; j < 8; ++j)
        ej[j] = en_lds[c * 256 + wn * 128 + j * 16 + l15];
#pragma unroll
      for (int k = 0; k < 16; ++k) {
        const int i = k >> 2, r = k & 3;
        float dd[8];
        float cm = FLT_MAX;
#pragma unroll
        for (int j = 0; j < 8; ++j) {
          dd[j] = fmaf(-2.f, acc[i][j][r], ej[j]);
          cm = fminf(cm, dd[j]);
        }
#pragma unroll
        for (int m = 1; m <= 8; m <<= 1) cm = fminf(cm, __shfl_xor(cm, m));
        minv[k] = fminf(minv[k], cm);
        const float thr = minv[k] + eps;
        const unsigned grow = (unsigned)(mt * FBM + wm * 64 + i * 16 + lq * 4 + r);
#pragma unroll
        for (int j = 0; j < 8; ++j) {
          if (dd[j] <= thr) {
            const unsigned slot = atomicAdd(&s_cnt, 1u);  // LDS atomic: fast
            if (slot < SLOTS) {
              const unsigned col = (unsigned)(c * 256 + wn * 128 + j * 16 + l15);
              myc[slot] = ((unsigned long long)((grow << 12) | col) << 32) |
                          __float_as_uint(dd[j]);
            }
          }
        }
      }
    }
  }
#undef STAGE_X2
#undef STAGE_E2

  // ================= fused resolve epilogue =================
  // Scratch overlays onto bufX (dead after the final barrier below).
  float* s_hmin = (float*)&bufX[0][0];                       // 1KB
  unsigned* s_live = (unsigned*)&bufX[0][1024];              // 1KB
  unsigned* s_col = (unsigned*)&bufX[0][2048];               // 1KB
  unsigned long long* s_res = (unsigned long long*)&bufX[0][4096];  // 2KB
  float* wsum = (float*)&bufX[0][8192];                      // 32B

#pragma unroll
  for (int k = 0; k < 16; ++k) {
    if (l15 == 0)
      argv_[wn][wm * 64 + (k >> 2) * 16 + lq * 4 + (k & 3)] = minv[k];
  }
  __threadfence_block();   // make this block's myc[] stores visible block-wide
  __syncthreads();         // all waves past final bufX reads; argv_ complete
  if (tid < FBM) {
    s_hmin[tid] = fminf(argv_[0][tid], argv_[1][tid]);
    s_live[tid] = 0u;
  }
  __syncthreads();
  const unsigned nc = (s_cnt < SLOTS) ? s_cnt : SLOTS;

  // phase A: mark live candidates (dd within eps of final hh-min)
  for (unsigned c = tid; c < nc; c += 512) {
    const unsigned long long ent = myc[c];
    const unsigned rc = (unsigned)(ent >> 32);
    const float dd = __uint_as_float((unsigned)(ent & 0xffffffffu));
    const unsigned lrow = (rc >> 12) & (FBM - 1);
    if (dd <= s_hmin[lrow] + eps) {
      atomicAdd(&s_live[lrow], 1u);
      s_col[lrow] = rc & 4095u;   // benign race; only used when live==1
    }
  }
  __syncthreads();
  if (tid < FBM && s_live[tid] >= 2) s_res[tid] = ~0ull;
  __syncthreads();

  // phase B: exact fp32 dot only for multi-candidate rows (wave per cand)
  for (unsigned c = wid; c < nc; c += 8) {
    const unsigned long long ent = myc[c];
    const unsigned rc = (unsigned)(ent >> 32);
    const float dd = __uint_as_float((unsigned)(ent & 0xffffffffu));
    const unsigned grow = rc >> 12;
    const unsigned lrow = grow & (FBM - 1);
    if (dd > s_hmin[lrow] + eps) continue;           // wave-uniform
    if (s_live[lrow] < 2) continue;                  // single: no dot needed
    const unsigned col = rc & 4095u;
    const float* xp = X + (size_t)grow * D_DIM + lane * 8;
    const float* ep = E + (size_t)col * D_DIM + lane * 8;
    float s = 0.f;
#pragma unroll
    for (int q = 0; q < 2; ++q) {
      const float4 xv = *(const float4*)(xp + q * 4);
      const float4 ev = *(const float4*)(ep + q * 4);
      s += xv.x * ev.x + xv.y * ev.y + xv.z * ev.z + xv.w * ev.w;
    }
#pragma unroll
    for (int m = 32; m >= 1; m >>= 1) s += __shfl_xor(s, m);
    if (lane == 0) {
      const float d = en[col] - 2.f * s + 8192.f;    // positive -> bit-monotone
      const unsigned long long pk =
          ((unsigned long long)__float_as_uint(d) << 32) | col;
      lds_min_u64(&s_res[lrow], pk);                 // ties -> lower col (np)
    }
  }
  __syncthreads();

  // phase C: gather + loss for this block's 256 rows
  float lsum = 0.f;
  const int sub = tid >> 7;           // 0..3
  const int c4 = (tid & 127) * 4;
  for (int r0 = 0; r0 < FBM; r0 += 4) {
    const int lrow = r0 + sub;
    const int row = mt * FBM + lrow;
    const int idx = (s_live[lrow] < 2) ? (int)s_col[lrow]
                                       : (int)(s_res[lrow] & 0xfffULL);
    const float4 ev = *(const float4*)(E + (size_t)idx * D_DIM + c4);
    const float4 xv = *(const float4*)(X + (size_t)row * D_DIM + c4);
    *(float4*)(outp + (size_t)row * D_DIM + c4) = ev;
    const float dx = ev.x - xv.x, dy = ev.y - xv.y, dz = ev.z - xv.z, dw = ev.w - xv.w;
    lsum += dx * dx + dy * dy + dz * dz + dw * dw;
  }
#pragma unroll
  for (int m = 32; m >= 1; m >>= 1) lsum += __shfl_xor(lsum, m);
  if (lane == 0) wsum[wid] = lsum;
  __syncthreads();
  if (tid == 0) {
    double t = 0.0;
#pragma unroll
    for (int w = 0; w < 8; ++w) t += (double)wsum[w];
    atomicAdd(loss_sum, t);
  }
}

// ---------------- finalize loss ----------------
__global__ void vq_finalize(const double* __restrict__ loss_sum, float* __restrict__ outp) {
  if (threadIdx.x == 0 && blockIdx.x == 0) {
    outp[(size_t)N_PTS * D_DIM] =
        (float)(1.25 * (*loss_sum) / ((double)N_PTS * (double)D_DIM));
  }
}

// ================= round-2 fallback kernels (ws too small) =================
#define BM 128
#define BN 128
#define NCHUNK 32
#define BK 32
#define NSTEP 16
#define NS (NCHUNK * NSTEP)

__device__ __forceinline__ void cvt_hl(const float4 v, f16x8& H, f16x8& L, const int b) {
  _Float16 h;
  h = (_Float16)v.x; H[b + 0] = h; L[b + 0] = (_Float16)(v.x - (float)h);
  h = (_Float16)v.y; H[b + 1] = h; L[b + 1] = (_Float16)(v.y - (float)h);
  h = (_Float16)v.z; H[b + 2] = h; L[b + 2] = (_Float16)(v.z - (float)h);
  h = (_Float16)v.w; H[b + 3] = h; L[b + 3] = (_Float16)(v.w - (float)h);
}

__global__ void vq_en_only(const float* __restrict__ E, float* __restrict__ en) {
  const int wave = threadIdx.x >> 6;
  const int lane = threadIdx.x & 63;
  const int row = blockIdx.x * 4 + wave;
  const float* src = E + (size_t)row * D_DIM;
  float s = 0.f;
#pragma unroll
  for (int h = 0; h < 2; ++h) {
    float4 v = *(const float4*)(src + h * 256 + lane * 4);
    s += v.x * v.x + v.y * v.y + v.z * v.z + v.w * v.w;
  }
#pragma unroll
  for (int m = 32; m >= 1; m >>= 1) s += __shfl_xor(s, m);
  if (lane == 0) en[row] = s;
}

__global__ __launch_bounds__(256, 2) void vq_main_r2(
    const float* __restrict__ X, const float* __restrict__ E,
    const float* __restrict__ en, float* __restrict__ outp,
    double* __restrict__ loss_sum) {
  __shared__ __align__(16) _Float16 Xh[BM][BK];
  __shared__ __align__(16) _Float16 Xl[BM][BK];
  __shared__ __align__(16) _Float16 Eh[BN][BK];
  __shared__ __align__(16) _Float16 El[BN][BK];
  __shared__ float rval[2][64][2];
  __shared__ int rixd[2][64][2];
  __shared__ int fin_idx[BM];
  __shared__ float wsum[4];

  const int tid = threadIdx.x;
  const int lane = tid & 63;
  const int wid = tid >> 6;
  const int wm = wid >> 1;
  const int wn = wid & 1;
  const int l15 = lane & 15;
  const int lq = lane >> 4;
  const int row0 = blockIdx.x * BM;

  const int srow = tid >> 1;
  const int seg16 = (tid & 1) * 16;
  const float* Xbase = X + (size_t)(row0 + srow) * D_DIM + seg16;

  float4 xgA[4], egA[4], xgB[4], egB[4];
#pragma unroll
  for (int e = 0; e < 4; ++e) xgA[e] = *(const float4*)(Xbase + e * 4);
  {
    const float* ep = E + (size_t)srow * D_DIM + seg16;
#pragma unroll
    for (int e = 0; e < 4; ++e) egA[e] = *(const float4*)(ep + e * 4);
  }

  float minv[16];
  int mini[16];
#pragma unroll
  for (int k = 0; k < 16; ++k) { minv[k] = FLT_MAX; mini[k] = 0; }

  f32x4 acc[4][4];
  float enj[4];

#define STEP(S, XG, EG, XGN, EGN)                                              \
  {                                                                            \
    const int t = (S) & (NSTEP - 1);                                           \
    const int chunk = (S) >> 4;                                                \
    if (t == 0) {                                                              \
      _Pragma("unroll") for (int j = 0; j < 4; ++j)                            \
          enj[j] = en[chunk * BN + wn * 64 + j * 16 + l15];                    \
      _Pragma("unroll") for (int i = 0; i < 4; ++i)                            \
          _Pragma("unroll") for (int j = 0; j < 4; ++j)                        \
              acc[i][j] = (f32x4)(0.f);                                        \
    }                                                                          \
    __syncthreads();                                                           \
    {                                                                          \
      f16x8 H0, H1, L0, L1;                                                    \
      cvt_hl(XG[0], H0, L0, 0); cvt_hl(XG[1], H0, L0, 4);                      \
      cvt_hl(XG[2], H1, L1, 0); cvt_hl(XG[3], H1, L1, 4);                      \
      *(f16x8*)&Xh[srow][seg16] = H0;                                          \
      *(f16x8*)&Xh[srow][seg16 + 8] = H1;                                      \
      *(f16x8*)&Xl[srow][seg16] = L0;                                          \
      *(f16x8*)&Xl[srow][seg16 + 8] = L1;                                      \
      cvt_hl(EG[0], H0, L0, 0); cvt_hl(EG[1], H0, L0, 4);                      \
      cvt_hl(EG[2], H1, L1, 0); cvt_hl(EG[3], H1, L1, 4);                      \
      *(f16x8*)&Eh[srow][seg16] = H0;                                          \
      *(f16x8*)&Eh[srow][seg16 + 8] = H1;                                      \
      *(f16x8*)&El[srow][seg16] = L0;                                          \
      *(f16x8*)&El[srow][seg16 + 8] = L1;                                      \
    }                                                                          \
    if ((S) + 1 < NS) {                                                        \
      const int t1 = ((S) + 1) & (NSTEP - 1);                                  \
      const int c1 = ((S) + 1) >> 4;                                           \
      const float* xp = Xbase + t1 * BK;                                       \
      const float* ep2 = E + (size_t)(c1 * BN + srow) * D_DIM + t1 * BK + seg16; \
      _Pragma("unroll") for (int e = 0; e < 4; ++e)                            \
          XGN[e] = *(const float4*)(xp + e * 4);                               \
      _Pragma("unroll") for (int e = 0; e < 4; ++e)                            \
          EGN[e] = *(const float4*)(ep2 + e * 4);                              \
    }                                                                          \
    __syncthreads();                                                           \
    {                                                                          \
      const int qo = lq * 8;                                                   \
      f16x8 bh[4], bl[4];                                                      \
      _Pragma("unroll") for (int j = 0; j < 4; ++j) {                          \
        bh[j] = *(const f16x8*)&Eh[wn * 64 + j * 16 + l15][qo];                \
        bl[j] = *(const f16x8*)&El[wn * 64 + j * 16 + l15][qo];                \
      }                                                                        \
      _Pragma("unroll") for (int i = 0; i < 4; ++i) {                          \
        const f16x8 ah = *(const f16x8*)&Xh[wm * 64 + i * 16 + l15][qo];       \
        const f16x8 al = *(const f16x8*)&Xl[wm * 64 + i * 16 + l15][qo];       \
        _Pragma("unroll") for (int j = 0; j < 4; ++j) {                        \
          acc[i][j] = __builtin_amdgcn_mfma_f32_16x16x32_f16(ah, bh[j], acc[i][j], 0, 0, 0); \
          acc[i][j] = __builtin_amdgcn_mfma_f32_16x16x32_f16(ah, bl[j], acc[i][j], 0, 0, 0); \
          acc[i][j] = __builtin_amdgcn_mfma_f32_16x16x32_f16(al, bh[j], acc[i][j], 0, 0, 0); \
        }                                                                      \
      }                                                                        \
    }                                                                          \
    if (t == NSTEP - 1) {                                                      \
      _Pragma("unroll") for (int i = 0; i < 4; ++i)                            \
          _Pragma("unroll") for (int j = 0; j < 4; ++j) {                      \
        const int c = chunk * BN + wn * 64 + j * 16 + l15;                     \
        _Pragma("unroll") for (int r = 0; r < 4; ++r) {                        \
          const float dd = fmaf(-2.f, acc[i][j][r], enj[j]);                   \
          const int k = i * 4 + r;                                             \
          if (dd < minv[k]) { minv[k] = dd; mini[k] = c; }                     \
        }                                                                      \
      }                                                                        \
    }                                                                          \
  }

  for (int s = 0; s < NS; s += 2) {
    STEP(s, xgA, egA, xgB, egB);
    STEP(s + 1, xgB, egB, xgA, egA);
  }
#undef STEP

#pragma unroll
  for (int k = 0; k < 16; ++k) {
    float v = minv[k];
    int ix = mini[k];
#pragma unroll
    for (int m = 1; m <= 8; m <<= 1) {
      const float v2 = __shfl_xor(v, m);
      const int ix2 = __shfl_xor(ix, m);
      if (v2 < v || (v2 == v && ix2 < ix)) { v = v2; ix = ix2; }
    }
    if (l15 == 0) {
      const int lrow = (k >> 2) * 16 + lq * 4 + (k & 3);
      rval[wm][lrow][wn] = v;
      rixd[wm][lrow][wn] = ix;
    }
  }
  __syncthreads();
  if (tid < BM) {
    const int wm_ = tid >> 6, lrow = tid & 63;
    const float v0 = rval[wm_][lrow][0], v1 = rval[wm_][lrow][1];
    const int i0 = rixd[wm_][lrow][0], i1 = rixd[wm_][lrow][1];
    fin_idx[tid] = (v1 < v0 || (v1 == v0 && i1 < i0)) ? i1 : i0;
  }
  __syncthreads();

  float lsum = 0.f;
  const int half = tid >> 7;
  const int c4 = (tid & 127) * 4;
  for (int r0 = 0; r0 < BM; r0 += 2) {
    const int r = r0 + half;
    const int idx = fin_idx[r];
    const float4 ev = *(const float4*)(E + (size_t)idx * D_DIM + c4);
    const float4 xv = *(const float4*)(X + (size_t)(row0 + r) * D_DIM + c4);
    *(float4*)(outp + (size_t)(row0 + r) * D_DIM + c4) = ev;
    const float dx = ev.x - xv.x, dy = ev.y - xv.y, dz = ev.z - xv.z, dw = ev.w - xv.w;
    lsum += dx * dx + dy * dy + dz * dz + dw * dw;
  }
#pragma unroll
  for (int m = 32; m >= 1; m >>= 1) lsum += __shfl_xor(lsum, m);
  if (lane == 0) wsum[wid] = lsum;
  __syncthreads();
  if (tid == 0) {
    const double t = (double)wsum[0] + (double)wsum[1] + (double)wsum[2] + (double)wsum[3];
    atomicAdd(loss_sum, t);
  }
}

extern "C" void kernel_launch(void* const* d_in, const int* in_sizes, int n_in,
                              void* d_out, int out_size, void* d_ws, size_t ws_size,
                              hipStream_t stream) {
  const float* X = (const float*)d_in[0];
  const float* E = (const float*)d_in[1];
  float* outp = (float*)d_out;

  // ---- ws layout (fast path) ----
  const size_t off_xpre = 0;
  const size_t sz_xpre = (size_t)4096 * TILE_HB;                 // 64 MB
  const size_t off_epre = off_xpre + sz_xpre;
  const size_t sz_epre = (size_t)256 * TILE_HB;                  // 4 MB
  const size_t off_en = off_epre + sz_epre;                      // 16 KB
  const size_t off_cand = off_en + (size_t)K_EMB * 4;            // 48 MB
  const size_t off_misc = off_cand + (size_t)NBLK * SLOTS * 8;   // 32 B
  const size_t need = off_misc + 32;

  if (ws_size >= need) {
    char* ws = (char*)d_ws;
    char* Xpre = ws + off_xpre;
    char* Epre = ws + off_epre;
    float* en = (float*)(ws + off_en);
    unsigned long long* cand = (unsigned long long*)(ws + off_cand);
    unsigned* enmax = (unsigned*)(ws + off_misc);
    unsigned* xnmax = enmax + 1;
    double* loss_sum = (double*)(ws + off_misc + 16);

    (void)hipMemsetAsync(ws + off_misc, 0, 32, stream);   // maxes, loss = 0

    hipLaunchKernelGGL(vq_prep, dim3(256), dim3(256), 0, stream,
                       X, E, Xpre, Epre, en, enmax, xnmax);
    hipLaunchKernelGGL(vq_screen, dim3(NBLK), dim3(512), 0, stream,
                       Xpre, Epre, en, enmax, xnmax, cand, X, E, outp, loss_sum);
    hipLaunchKernelGGL(vq_finalize, dim3(1), dim3(64), 0, stream, loss_sum, outp);
  } else {
    float* en = (float*)d_ws;
    double* loss_sum = (double*)((char*)d_ws + K_EMB * sizeof(float));

    (void)hipMemsetAsync(loss_sum, 0, sizeof(double), stream);
    hipLaunchKernelGGL(vq_en_only, dim3(K_EMB / 4), dim3(256), 0, stream, E, en);
    hipLaunchKernelGGL(vq_main_r2, dim3(N_PTS / BM), dim3(256), 0, stream,
                       X, E, en, outp, loss_sum);
    hipLaunchKernelGGL(vq_finalize, dim3(1), dim3(64), 0, stream, loss_sum, outp);
  }
}